// Round 16
// baseline (6713.576 us; speedup 1.0000x reference)
//
#include <hip/hip_runtime.h>
#include <math.h>

// ---------------------------------------------------------------------------
// 2-layer tanh RNN scan, B=128, T=1024, H=768.  Persistent kernel, 256 WGs.
// Round-16 = round-15 with SINGLE-COLLECTOR rendezvous:
//   * arrive: ONE global_atomic_swap of own flag.  No poll in arrive path.
//   * collector (fL1: L1 WG c=0; fH2: L2 WG q=0) raw-polls its flag array
//     alone inside its own wait (distinct addresses, zero contention) and on
//     detect publishes min to 32 per-WG epoch replicas (64B apart, umax,
//     lanes 0..31 in parallel).  Collector reaches that wait every step =>
//     publish lag ~ one poll interval after last arrival.
//   * subscribers poll ONLY their private replica (lane0, 1 RMW/round,
//     1 poller/address); sparse raw failsafe every 64th round.
// Everything else r14/r15-verbatim (all proven): sc0 data stores -> XCD L2,
// tid0 buffer_inv acquire + plain L2-hit loads, atomic P reads, 4-slot h1 /
// 2-slot h2 / 4-slot P dep graph, bf16 hi/lo 3-product MFMA numerics,
// agent-scope fallback (r10) for non-co-resident groups.
// ---------------------------------------------------------------------------

typedef short s16x8 __attribute__((ext_vector_type(8)));
typedef float fx4   __attribute__((ext_vector_type(4)));

#define NWG    256
#define T_LEN  1024
#define H      768
#define GROUPS 8
#define GROWS  16

// ws layout (bytes)
#define MAP_OFF    0          // u32[256]
#define KBR_OFF    1024       // u32[256]
#define GRP_BASE   8192
#define G_FL1 0               // u32[8]
#define G_FH2 128             // u32[24]
#define G_EL1 512             // 32 epoch replicas x 64B = 2048
#define G_EH2 2560            // 32 epoch replicas x 64B = 2048
#define G_PB  4608            // float[4][16][2][24] = 12288B (ends 16896)
#define G_H1  20480           // 4 slots x {hi,lo} x 24576B (ends 217088)
#define G_H2  217088          // 2 slots x {hi,lo} x 24576B (ends 315392)
#define GRP_STRIDE 315392
#define HB_SZ 24576
#define WS_TOTAL (GRP_BASE + GROUPS * GRP_STRIDE)

__device__ __forceinline__ unsigned short f2bf(float x) {
    unsigned u = __float_as_uint(x);
    unsigned r = (u + 0x7FFFu + ((u >> 16) & 1u)) >> 16;   // RNE
    return (unsigned short)r;
}
__device__ __forceinline__ float bf2f(unsigned short b) {
    return __uint_as_float(((unsigned)b) << 16);
}
__device__ __forceinline__ fx4 mfma16(s16x8 a, s16x8 b, fx4 c) {
    return __builtin_amdgcn_mfma_f32_16x16x32_bf16(a, b, c, 0, 0, 0);
}

// ---- AGENT primitives (r10-proven) -----------------------------------------
__device__ __forceinline__ void st_ag(unsigned* p, unsigned v) {
    __hip_atomic_store(p, v, __ATOMIC_RELAXED, __HIP_MEMORY_SCOPE_AGENT);
}
__device__ __forceinline__ unsigned ld_ag(const unsigned* p) {
    return __hip_atomic_load(p, __ATOMIC_RELAXED, __HIP_MEMORY_SCOPE_AGENT);
}
__device__ __forceinline__ void acq_ag() {
    __builtin_amdgcn_fence(__ATOMIC_ACQUIRE, "agent");
}
// ---- LOCAL primitives (XCD-L2 scope; r12/r14/r15-proven) -------------------
__device__ __forceinline__ void st32_sc0(unsigned* p, unsigned v) {
    asm volatile("global_store_dword %0, %1, off sc0" :: "v"(p), "v"(v) : "memory");
}
__device__ __forceinline__ void stflag_l2(unsigned* p, unsigned v) {
    asm volatile("global_atomic_swap %0, %1, off" :: "v"(p), "v"(v) : "memory");
}
__device__ __forceinline__ void umax_l2(unsigned* p, unsigned v) {
    asm volatile("global_atomic_umax %0, %1, off" :: "v"(p), "v"(v) : "memory");
}
__device__ __forceinline__ unsigned rdflag_l2(unsigned* p) {
    unsigned v, z = 0;
    asm volatile("global_atomic_add %0, %1, %2, off sc0\n\ts_waitcnt vmcnt(0)"
                 : "=v"(v) : "v"(p), "v"(z) : "memory");
    return v;
}
__device__ __forceinline__ void inv_l1() {     // CU L1 invalidate (L2 intact)
    asm volatile("buffer_inv sc0" ::: "memory");
}

template<bool LOCAL> __device__ __forceinline__ unsigned rdp(unsigned* p) {
    if constexpr (LOCAL) return rdflag_l2(p); else return ld_ag(p);
}
template<bool LOCAL> __device__ __forceinline__ void std32(unsigned* p, unsigned v) {
    if constexpr (LOCAL) st32_sc0(p, v); else st_ag(p, v);
}

__device__ __forceinline__ void load_wfrag(const float* __restrict__ W,
                                           int col, int kk, s16x8& hi, s16x8& lo) {
    const float* p = W + (long)col * H + kk;
#pragma unroll
    for (int j = 0; j < 8; j++) {
        float w = p[j];
        unsigned short h = f2bf(w);
        float r = w - bf2f(h);
        hi[j] = (short)h;
        lo[j] = (short)f2bf(r);
    }
}

__device__ __forceinline__ void ld6(const unsigned short* p, s16x8 (&d)[6]) {
#pragma unroll
    for (int ks = 0; ks < 6; ks++)
        d[ks] = *reinterpret_cast<const s16x8*>(p + ks * 32);
}

__device__ __forceinline__ unsigned wave_min(unsigned v) {
#pragma unroll
    for (int o = 32; o; o >>= 1) {
        unsigned u = (unsigned)__shfl_xor((int)v, o);
        v = v < u ? v : u;
    }
    return v;
}

// COLLECTOR wait: raw-poll alone (distinct addrs); publish min to the 32
// epoch replicas on detect; optional inv acquire; syncthreads; cached.
__device__ __forceinline__ unsigned wait_col(unsigned* raw, int n, unsigned T,
                                             int tid, unsigned* reps,
                                             unsigned cached, bool do_inv,
                                             volatile unsigned* sh) {
    if (cached < T) {
        if (tid < 64) {
            unsigned m;
            long spin = 0;
            for (;;) {
                unsigned v = (tid < n) ? rdflag_l2(raw + tid) : 0xFFFFFFFFu;
                m = wave_min(v);
                if (m >= T) break;
                __builtin_amdgcn_s_sleep(1);
                if (++spin > (1L << 20)) break;   // failsafe
            }
            if (tid < 32) umax_l2(reps + tid * 16, m);
            if (tid == 0) *sh = m;
        }
    }
    if (do_inv && tid == 0) inv_l1();
    __syncthreads();
    return (cached < T) ? *sh : cached;
}

// SUBSCRIBER wait: lane0 polls own replica (1 RMW/round, 1 poller/address);
// raw failsafe every 64th round; optional inv acquire; syncthreads; cached.
__device__ __forceinline__ unsigned wait_sub(unsigned* reps, unsigned* raw, int n,
                                             unsigned T, int tid, int lrank,
                                             unsigned cached, bool do_inv,
                                             volatile unsigned* sh) {
    if (cached < T) {
        if (tid < 64) {
            unsigned* myrep = reps + lrank * 16;
            unsigned m = 0;
            long spin = 0;
            for (;;) {
                if ((spin & 63) == 63) {
                    unsigned v = (tid < n) ? rdflag_l2(raw + tid) : 0xFFFFFFFFu;
                    m = wave_min(v);
                } else {
                    if (tid == 0) m = rdflag_l2(myrep);
                    m = (unsigned)__shfl((int)m, 0);
                }
                if (m >= T) break;
                __builtin_amdgcn_s_sleep(1);
                if (++spin > (1L << 20)) break;   // failsafe
            }
            if (tid == 0) *sh = m;
        }
    }
    if (do_inv && tid == 0) inv_l1();
    __syncthreads();
    return (cached < T) ? *sh : cached;
}

// AGENT wait: r10 verbatim.
__device__ __forceinline__ void wait_agent(unsigned* f, int n, unsigned T,
                                           int tid, bool acquire) {
    if (tid < 64) {
        int l = tid < n ? tid : n - 1;
        long spin = 0;
        for (;;) {
            if (wave_min(ld_ag(f + l)) >= T) break;
            __builtin_amdgcn_s_sleep(1);
            if (++spin > (1L << 20)) break;
        }
    }
    if (acquire && tid == 0) acq_ag();
    __syncthreads();
}

#define DRAIN() do { asm volatile("s_waitcnt vmcnt(0)" ::: "memory"); __syncthreads(); } while (0)

// ---------------------------------------------------------------------------
template<bool LOCAL>
__device__ __forceinline__ void run_group(
    int group, int lrank, int tid, int lane, int w, int l15, int lk8,
    const float* __restrict__ x,
    const float* __restrict__ Wih1, const float* __restrict__ Whh1,
    const float* __restrict__ bih1, const float* __restrict__ bhh1,
    const float* __restrict__ Wih2, const float* __restrict__ Whh2,
    const float* __restrict__ bih2, const float* __restrict__ bhh2,
    const float* __restrict__ Wlin, const float* __restrict__ blin,
    float* __restrict__ out, unsigned char* __restrict__ gb,
    float (*red)[16][97], volatile unsigned* shm)
{
    unsigned* fL1 = (unsigned*)(gb + G_FL1);
    unsigned* fH2 = (unsigned*)(gb + G_FH2);
    unsigned* eL1 = (unsigned*)(gb + G_EL1);
    unsigned* eH2 = (unsigned*)(gb + G_EH2);
    float*    Pb  = (float*)(gb + G_PB);       // [4][16][2][24]
    const int kb0 = w * 192;

    if (lrank < 8) {
        // ========================= L1 role ==================================
        const int c = lrank;
        const int col0 = c * 96;

        s16x8 whi[6][6], wlo[6][6];
#pragma unroll
        for (int ks = 0; ks < 6; ks++)
#pragma unroll
            for (int nt = 0; nt < 6; nt++)
                load_wfrag(Whh1, col0 + nt * 16 + l15, kb0 + ks * 32 + lk8,
                           whi[ks][nt], wlo[ks][nt]);

        const int er = tid >> 4;                // row 0..15
        const int ec0 = (tid & 15) * 6;         // 6 consecutive cols
        const int b = group * GROWS + er;
        float bs[6], wi0[6], wi1[6];
#pragma unroll
        for (int j = 0; j < 6; j++) {
            int cg = col0 + ec0 + j;
            bs[j] = bih1[cg] + bhh1[cg];
            wi0[j] = Wih1[cg * 2 + 0];
            wi1[j] = Wih1[cg * 2 + 1];
        }
        const int ov = tid >> 5;                // 0..3 (tid<128)
        const int oj = tid & 31;
        const int orow = 2 * c + (ov >> 1);
        const int ooo = ov & 1;
        const float blv = blin[ooo];

        unsigned fh2c = 0, fl1c = 0;

        for (int t = 0; t < T_LEN; t++) {
            const int rs = (t + 3) & 3;         // h1(t-1) slot
            const int wsl = t & 3;              // h1(t) slot
            float x0 = x[b * 2048 + t];
            float x1 = x[b * 2048 + 1024 + t];

            // Top-of-iter off-path: fH2 gate (h1-slot guard) + out(t-3).
            // No inv: P read via atomics; slot guard is write-only.
            if (t >= 3) {
                if constexpr (LOCAL)
                    fh2c = wait_sub(eH2, fH2, 24, (unsigned)(t - 2), tid, lrank, fh2c, false, &shm[0]);
                else
                    wait_agent(fH2, 24, (unsigned)(t - 2), tid, false);
                if (tid < 128) {
                    float p = 0.f;
                    if (oj < 24)
                        p = __uint_as_float(rdp<LOCAL>((unsigned*)
                            (Pb + ((((t - 3) & 3) * 16 + orow) * 2 + ooo) * 24 + oj)));
#pragma unroll
                    for (int o = 16; o; o >>= 1) p += __shfl_down(p, o, 32);
                    if (oj == 0) out[(group * GROWS + orow) * 2048 + ooo * 1024 + (t - 3)] = p + blv;
                }
            }

            if (t) {
                if constexpr (LOCAL) {
                    if (c == 0)
                        fl1c = wait_col(fL1, 8, (unsigned)t, tid, eL1, fl1c, true, &shm[1]);
                    else
                        fl1c = wait_sub(eL1, fL1, 8, (unsigned)t, tid, lrank, fl1c, true, &shm[1]);
                } else {
                    wait_agent(fL1, 8, (unsigned)t, tid, true);
                }
            }

            const unsigned short* Hh = (const unsigned short*)(gb + G_H1 + rs * 2 * HB_SZ);
            const unsigned short* Hl = (const unsigned short*)(gb + G_H1 + rs * 2 * HB_SZ + HB_SZ);
            s16x8 ah[6], al[6];
            ld6(Hh + l15 * H + kb0 + lk8, ah);
            ld6(Hl + l15 * H + kb0 + lk8, al);

            fx4 acc[6];
#pragma unroll
            for (int nt = 0; nt < 6; nt++) acc[nt] = fx4{0.f, 0.f, 0.f, 0.f};
#pragma unroll
            for (int ks = 0; ks < 6; ks++)
#pragma unroll
                for (int nt = 0; nt < 6; nt++) {
                    acc[nt] = mfma16(ah[ks], whi[ks][nt], acc[nt]);
                    acc[nt] = mfma16(ah[ks], wlo[ks][nt], acc[nt]);
                    acc[nt] = mfma16(al[ks], whi[ks][nt], acc[nt]);
                }

#pragma unroll
            for (int nt = 0; nt < 6; nt++)
#pragma unroll
                for (int i = 0; i < 4; i++)
                    red[w][(lane >> 4) * 4 + i][nt * 16 + l15] = acc[nt][i];
            __syncthreads();

            unsigned hw[3], lw[3];
#pragma unroll
            for (int jj = 0; jj < 3; jj++) {
                unsigned hp = 0, lp = 0;
#pragma unroll
                for (int k = 0; k < 2; k++) {
                    int j = jj * 2 + k;
                    int cc = ec0 + j;
                    float v = red[0][er][cc] + red[1][er][cc] + red[2][er][cc] + red[3][er][cc];
                    v += x0 * wi0[j] + x1 * wi1[j] + bs[j];
                    v = tanhf(v);
                    unsigned short hb = f2bf(v);
                    unsigned short lb = f2bf(v - bf2f(hb));
                    hp |= ((unsigned)hb) << (16 * k);
                    lp |= ((unsigned)lb) << (16 * k);
                }
                hw[jj] = hp; lw[jj] = lp;
            }

            unsigned* Dh = (unsigned*)(gb + G_H1 + wsl * 2 * HB_SZ) + ((long)er * H + col0 + ec0) / 2;
            unsigned* Dl = (unsigned*)(gb + G_H1 + wsl * 2 * HB_SZ + HB_SZ) + ((long)er * H + col0 + ec0) / 2;
            std32<LOCAL>(Dh + 0, hw[0]); std32<LOCAL>(Dh + 1, hw[1]); std32<LOCAL>(Dh + 2, hw[2]);
            std32<LOCAL>(Dl + 0, lw[0]); std32<LOCAL>(Dl + 1, lw[1]); std32<LOCAL>(Dl + 2, lw[2]);

            DRAIN();
            if (tid == 0) {
                if constexpr (LOCAL) stflag_l2(fL1 + c, (unsigned)(t + 1));
                else st_ag(fL1 + c, (unsigned)(t + 1));
            }
        }

        // tail: P(T-3..T-1)
        if constexpr (LOCAL)
            fh2c = wait_col(fH2, 24, (unsigned)T_LEN, tid, eH2, fh2c, false, &shm[0]);
        else
            wait_agent(fH2, 24, (unsigned)T_LEN, tid, false);
        if (tid < 128) {
#pragma unroll
            for (int par = 0; par < 3; par++) {
                int tt = T_LEN - 3 + par;
                float p = 0.f;
                if (oj < 24)
                    p = __uint_as_float(rdp<LOCAL>((unsigned*)
                        (Pb + (((tt & 3) * 16 + orow) * 2 + ooo) * 24 + oj)));
#pragma unroll
                for (int o = 16; o; o >>= 1) p += __shfl_down(p, o, 32);
                if (oj == 0) out[(group * GROWS + orow) * 2048 + ooo * 1024 + tt] = p + blv;
            }
        }
    } else {
        // ========================= L2 role ==================================
        const int q = lrank - 8;         // 0..23
        const int col0 = q * 32;

        s16x8 ghi[2][6], glo[2][6], ihi[2][6], ilo[2][6];
#pragma unroll
        for (int nt = 0; nt < 2; nt++)
#pragma unroll
            for (int ks = 0; ks < 6; ks++) {
                load_wfrag(Whh2, col0 + nt * 16 + l15, kb0 + ks * 32 + lk8, ghi[nt][ks], glo[nt][ks]);
                load_wfrag(Wih2, col0 + nt * 16 + l15, kb0 + ks * 32 + lk8, ihi[nt][ks], ilo[nt][ks]);
            }

        const int er = tid >> 4;             // 0..15
        const int ec0 = (tid & 15) * 2;      // 0..30
        const float bsA = bih2[col0 + ec0] + bhh2[col0 + ec0];
        const float bsB = bih2[col0 + ec0 + 1] + bhh2[col0 + ec0 + 1];

        const int ro = tid >> 1, oo = tid & 1;   // tid<32
        float wl[32];
        if (tid < 32) {
#pragma unroll
            for (int cc = 0; cc < 32; cc++) wl[cc] = Wlin[oo * H + col0 + cc];
        }

        unsigned fh2c = 0, fl1c = 0;

        for (int t = 0; t < T_LEN; t++) {
            const int rb = (t + 1) & 1;     // h2(t-1) slot
            const int wb = t & 1;           // h2(t) slot
            const int hs = t & 3;           // h1(t) slot

            if (t) {
                if constexpr (LOCAL) {
                    if (q == 0)
                        fh2c = wait_col(fH2, 24, (unsigned)t, tid, eH2, fh2c, true, &shm[2]);
                    else
                        fh2c = wait_sub(eH2, fH2, 24, (unsigned)t, tid, lrank, fh2c, true, &shm[2]);
                } else {
                    wait_agent(fH2, 24, (unsigned)t, tid, true);
                }
            }

            // phase 1: h2(t-1) @ W_hh2^T (overlaps h1(t) production)
            const unsigned short* Gh = (const unsigned short*)(gb + G_H2 + rb * 2 * HB_SZ);
            const unsigned short* Gl = (const unsigned short*)(gb + G_H2 + rb * 2 * HB_SZ + HB_SZ);
            s16x8 ah[6], al[6];
            ld6(Gh + l15 * H + kb0 + lk8, ah);
            ld6(Gl + l15 * H + kb0 + lk8, al);

            fx4 a2[2];
            a2[0] = fx4{0.f, 0.f, 0.f, 0.f};
            a2[1] = fx4{0.f, 0.f, 0.f, 0.f};
#pragma unroll
            for (int ks = 0; ks < 6; ks++)
#pragma unroll
                for (int nt = 0; nt < 2; nt++) {
                    a2[nt] = mfma16(ah[ks], ghi[nt][ks], a2[nt]);
                    a2[nt] = mfma16(ah[ks], glo[nt][ks], a2[nt]);
                    a2[nt] = mfma16(al[ks], ghi[nt][ks], a2[nt]);
                }

            if constexpr (LOCAL)
                fl1c = wait_sub(eL1, fL1, 8, (unsigned)(t + 1), tid, lrank, fl1c, true, &shm[3]);
            else
                wait_agent(fL1, 8, (unsigned)(t + 1), tid, true);

            // phase 3: += h1(t) @ W_ih2^T
            const unsigned short* Hh = (const unsigned short*)(gb + G_H1 + hs * 2 * HB_SZ);
            const unsigned short* Hl = (const unsigned short*)(gb + G_H1 + hs * 2 * HB_SZ + HB_SZ);
            ld6(Hh + l15 * H + kb0 + lk8, ah);
            ld6(Hl + l15 * H + kb0 + lk8, al);
#pragma unroll
            for (int ks = 0; ks < 6; ks++)
#pragma unroll
                for (int nt = 0; nt < 2; nt++) {
                    a2[nt] = mfma16(ah[ks], ihi[nt][ks], a2[nt]);
                    a2[nt] = mfma16(ah[ks], ilo[nt][ks], a2[nt]);
                    a2[nt] = mfma16(al[ks], ihi[nt][ks], a2[nt]);
                }

#pragma unroll
            for (int nt = 0; nt < 2; nt++)
#pragma unroll
                for (int i = 0; i < 4; i++)
                    red[w][(lane >> 4) * 4 + i][nt * 16 + l15] = a2[nt][i];
            __syncthreads();

            float v0 = red[0][er][ec0] + red[1][er][ec0] + red[2][er][ec0] + red[3][er][ec0] + bsA;
            float v1 = red[0][er][ec0 + 1] + red[1][er][ec0 + 1] + red[2][er][ec0 + 1] + red[3][er][ec0 + 1] + bsB;
            v0 = tanhf(v0); v1 = tanhf(v1);
            unsigned short hb0 = f2bf(v0), hb1 = f2bf(v1);
            unsigned hp = ((unsigned)hb0) | (((unsigned)hb1) << 16);
            unsigned lp = ((unsigned)f2bf(v0 - bf2f(hb0))) | (((unsigned)f2bf(v1 - bf2f(hb1))) << 16);
            unsigned* Dh = (unsigned*)(gb + G_H2 + wb * 2 * HB_SZ) + ((long)er * H + col0 + ec0) / 2;
            unsigned* Dl = (unsigned*)(gb + G_H2 + wb * 2 * HB_SZ + HB_SZ) + ((long)er * H + col0 + ec0) / 2;
            std32<LOCAL>(Dh, hp);
            std32<LOCAL>(Dl, lp);
            red[0][er][ec0] = v0;
            red[0][er][ec0 + 1] = v1;
            __syncthreads();

            if (tid < 32) {
                float s = 0.f;
#pragma unroll
                for (int cc = 0; cc < 32; cc++) s += red[0][ro][cc] * wl[cc];
                std32<LOCAL>((unsigned*)&Pb[(((t & 3) * 16 + ro) * 2 + oo) * 24 + q],
                             __float_as_uint(s));
            }

            DRAIN();
            if (tid == 0) {
                if constexpr (LOCAL) stflag_l2(fH2 + q, (unsigned)(t + 1));
                else st_ag(fH2 + q, (unsigned)(t + 1));
            }
        }
    }
}

// ---------------------------------------------------------------------------
__global__ __launch_bounds__(256, 1) void rnn_persist(
    const float* __restrict__ x,
    const float* __restrict__ Wih1, const float* __restrict__ Whh1,
    const float* __restrict__ bih1, const float* __restrict__ bhh1,
    const float* __restrict__ Wih2, const float* __restrict__ Whh2,
    const float* __restrict__ bih2, const float* __restrict__ bhh2,
    const float* __restrict__ Wlin, const float* __restrict__ blin,
    float* __restrict__ out, unsigned char* __restrict__ ws)
{
    const int wg = blockIdx.x;
    const int tid = threadIdx.x;
    const int lane = tid & 63;
    const int w = tid >> 6;
    const int l15 = lane & 15;
    const int lk8 = (lane >> 4) * 8;

    __shared__ float red[4][16][97];
    __shared__ int iscr[256];
    __shared__ unsigned shm[4];

    // ---- runtime XCD discovery (agent scope, r5/r6/r12-proven) -------------
    unsigned* map = (unsigned*)(ws + MAP_OFF);
    unsigned* kbr = (unsigned*)(ws + KBR_OFF);

    int key;
    asm volatile("s_getreg_b32 %0, hwreg(HW_REG_XCC_ID, 0, 4)" : "=s"(key));
    key &= 0xF;

    if (tid == 0) st_ag(map + wg, (unsigned)(key + 1));
    unsigned kj;
    {
        long spin = 0;
        for (;;) {
            kj = ld_ag(map + tid);
            if (kj) break;
            __builtin_amdgcn_s_sleep(2);
            if (++spin > (1L << 20)) break;
        }
    }
    int contrib = (((int)kj - 1) < key || (((int)kj - 1) == key && tid < wg)) ? 1 : 0;
    iscr[tid] = contrib;
    __syncthreads();
#pragma unroll
    for (int s = 128; s; s >>= 1) {
        if (tid < s) iscr[tid] += iscr[tid + s];
        __syncthreads();
    }
    const int rank = iscr[0];
    __syncthreads();
    const int group = rank >> 5, lrank = rank & 31;

    if (tid == 0) st_ag(kbr + rank, (unsigned)(key + 1));
    unsigned kv;
    {
        long spin = 0;
        for (;;) {
            kv = ld_ag(kbr + tid);
            if (kv) break;
            __builtin_amdgcn_s_sleep(2);
            if (++spin > (1L << 20)) break;
        }
    }
    int eq = ((int)kv - 1 == key) ? 1 : 0;
    int bad = ((tid >> 5) == group && !eq) ? 1 : 0;
    iscr[tid] = eq | (bad << 16);
    __syncthreads();
#pragma unroll
    for (int s = 128; s; s >>= 1) {
        if (tid < s) iscr[tid] += iscr[tid + s];
        __syncthreads();
    }
    const int r0 = iscr[0];
    __syncthreads();
    const bool local = ((r0 & 0xFFFF) == 32) && ((r0 >> 16) == 0);

    unsigned char* gb = ws + GRP_BASE + (size_t)group * GRP_STRIDE;

    if (local)
        run_group<true>(group, lrank, tid, lane, w, l15, lk8,
                        x, Wih1, Whh1, bih1, bhh1, Wih2, Whh2, bih2, bhh2,
                        Wlin, blin, out, gb, red, shm);
    else
        run_group<false>(group, lrank, tid, lane, w, l15, lk8,
                         x, Wih1, Whh1, bih1, bhh1, Wih2, Whh2, bih2, bhh2,
                         Wlin, blin, out, gb, red, shm);
}

extern "C" void kernel_launch(void* const* d_in, const int* in_sizes, int n_in,
                              void* d_out, int out_size, void* d_ws, size_t ws_size,
                              hipStream_t stream) {
    const float* x    = (const float*)d_in[0];
    const float* Wih1 = (const float*)d_in[1];
    const float* Whh1 = (const float*)d_in[2];
    const float* bih1 = (const float*)d_in[3];
    const float* bhh1 = (const float*)d_in[4];
    const float* Wih2 = (const float*)d_in[5];
    const float* Whh2 = (const float*)d_in[6];
    const float* bih2 = (const float*)d_in[7];
    const float* bhh2 = (const float*)d_in[8];
    const float* Wlin = (const float*)d_in[9];
    const float* blin = (const float*)d_in[10];

    // Zero discovery tables, flags, epochs, h-state (initial h = 0).
    hipMemsetAsync(d_ws, 0, WS_TOTAL, stream);

    rnn_persist<<<NWG, 256, 0, stream>>>(x, Wih1, Whh1, bih1, bhh1,
                                         Wih2, Whh2, bih2, bhh2,
                                         Wlin, blin, (float*)d_out,
                                         (unsigned char*)d_ws);
}

// Round 17
// 6473.099 us; speedup vs baseline: 1.0372x; 1.0372x over previous
//
#include <hip/hip_runtime.h>
#include <math.h>

// ---------------------------------------------------------------------------
// 2-layer tanh RNN scan, B=128, T=1024, H=768.  Persistent kernel, 256 WGs.
// Round-17 = round-15 (best: 6.46 ms) with critical-chain compression:
//   * SPLIT FLAGS: fH2d = h2-data ready (arrive right after h2-store DRAIN;
//     epoch-published, r15 arrive_pub).  fP = P partials committed (plain
//     swap after P DRAIN).  The h2 recurrence chain no longer carries the
//     P-dot + second DRAIN.  L1's slot-guard/out-gate -> fP (cached raw poll,
//     usually skipped).  Audit: fH2d>=t covers peers' phase1(t-1) reads =>
//     h2-slot anti-dep OK; fP>=x => fH2d>=x (same-WG order); P race still
//     gated by fL1 (unchanged).
//   * ONE buffer_inv per L2 iter (at the fH2d wait) — the fL1 wait loses its
//     inv (no h1-address refetch between; first-touch covers t=0).
//   * h1 PREFETCH fast-path: if cached fL1 >= t+1, load h1 with h2 so its
//     latency hides under phase1 MFMAs; poll only when cache stale.
// Data path & numerics r14/r15-proven: sc0 stores -> XCD L2; plain L2-hit
// loads after inv; atomic P reads; bf16 hi/lo 3-product MFMA; AGENT fallback.
// ---------------------------------------------------------------------------

typedef short s16x8 __attribute__((ext_vector_type(8)));
typedef float fx4   __attribute__((ext_vector_type(4)));

#define NWG    256
#define T_LEN  1024
#define H      768
#define GROUPS 8
#define GROWS  16

// ws layout (bytes)
#define MAP_OFF    0          // u32[256]
#define KBR_OFF    1024       // u32[256]
#define GRP_BASE   8192
#define G_FL1  0              // u32[8]
#define G_FH2D 128            // u32[24]
#define G_FP   256            // u32[24]
#define G_EL1  512            // 32 epoch replicas x 64B = 2048
#define G_EH2D 2560           // 32 epoch replicas x 64B = 2048
#define G_PB   4608           // float[4][16][2][24] = 12288B (ends 16896)
#define G_H1   20480          // 4 slots x {hi,lo} x 24576B (ends 217088)
#define G_H2   217088         // 2 slots x {hi,lo} x 24576B (ends 315392)
#define GRP_STRIDE 315392
#define HB_SZ 24576
#define WS_TOTAL (GRP_BASE + GROUPS * GRP_STRIDE)

__device__ __forceinline__ unsigned short f2bf(float x) {
    unsigned u = __float_as_uint(x);
    unsigned r = (u + 0x7FFFu + ((u >> 16) & 1u)) >> 16;   // RNE
    return (unsigned short)r;
}
__device__ __forceinline__ float bf2f(unsigned short b) {
    return __uint_as_float(((unsigned)b) << 16);
}
__device__ __forceinline__ fx4 mfma16(s16x8 a, s16x8 b, fx4 c) {
    return __builtin_amdgcn_mfma_f32_16x16x32_bf16(a, b, c, 0, 0, 0);
}

// ---- AGENT primitives (r10-proven) -----------------------------------------
__device__ __forceinline__ void st_ag(unsigned* p, unsigned v) {
    __hip_atomic_store(p, v, __ATOMIC_RELAXED, __HIP_MEMORY_SCOPE_AGENT);
}
__device__ __forceinline__ unsigned ld_ag(const unsigned* p) {
    return __hip_atomic_load(p, __ATOMIC_RELAXED, __HIP_MEMORY_SCOPE_AGENT);
}
__device__ __forceinline__ void acq_ag() {
    __builtin_amdgcn_fence(__ATOMIC_ACQUIRE, "agent");
}
// ---- LOCAL primitives (XCD-L2 scope; r12/r14/r15-proven) -------------------
__device__ __forceinline__ void st32_sc0(unsigned* p, unsigned v) {
    asm volatile("global_store_dword %0, %1, off sc0" :: "v"(p), "v"(v) : "memory");
}
__device__ __forceinline__ void stflag_l2(unsigned* p, unsigned v) {
    asm volatile("global_atomic_swap %0, %1, off" :: "v"(p), "v"(v) : "memory");
}
__device__ __forceinline__ void umax_l2(unsigned* p, unsigned v) {
    asm volatile("global_atomic_umax %0, %1, off" :: "v"(p), "v"(v) : "memory");
}
__device__ __forceinline__ unsigned rdflag_l2(unsigned* p) {
    unsigned v, z = 0;
    asm volatile("global_atomic_add %0, %1, %2, off sc0\n\ts_waitcnt vmcnt(0)"
                 : "=v"(v) : "v"(p), "v"(z) : "memory");
    return v;
}
__device__ __forceinline__ void inv_l1() {     // CU L1 invalidate (L2 intact)
    asm volatile("buffer_inv sc0" ::: "memory");
}

template<bool LOCAL> __device__ __forceinline__ unsigned rdp(unsigned* p) {
    if constexpr (LOCAL) return rdflag_l2(p); else return ld_ag(p);
}
template<bool LOCAL> __device__ __forceinline__ void std32(unsigned* p, unsigned v) {
    if constexpr (LOCAL) st32_sc0(p, v); else st_ag(p, v);
}

__device__ __forceinline__ void load_wfrag(const float* __restrict__ W,
                                           int col, int kk, s16x8& hi, s16x8& lo) {
    const float* p = W + (long)col * H + kk;
#pragma unroll
    for (int j = 0; j < 8; j++) {
        float w = p[j];
        unsigned short h = f2bf(w);
        float r = w - bf2f(h);
        hi[j] = (short)h;
        lo[j] = (short)f2bf(r);
    }
}

__device__ __forceinline__ void ld6(const unsigned short* p, s16x8 (&d)[6]) {
#pragma unroll
    for (int ks = 0; ks < 6; ks++)
        d[ks] = *reinterpret_cast<const s16x8*>(p + ks * 32);
}

__device__ __forceinline__ unsigned wave_min(unsigned v) {
#pragma unroll
    for (int o = 32; o; o >>= 1) {
        unsigned u = (unsigned)__shfl_xor((int)v, o);
        v = v < u ? v : u;
    }
    return v;
}

// r15 arrive + epoch publish (proven best): own swap; vmcnt; one raw poll
// round; publish min to 32 replicas iff min >= own value.
__device__ __forceinline__ void arrive_pub(unsigned* own, unsigned ownval,
                                           unsigned* raw, int n, int ownidx,
                                           unsigned* reps, int tid) {
    if (tid == 0) stflag_l2(own, ownval);
    if (tid < 64) {
        asm volatile("s_waitcnt vmcnt(0)" ::: "memory");
        unsigned v = 0xFFFFFFFFu;
        if (tid < n) v = (tid == ownidx) ? ownval : rdflag_l2(raw + tid);
        unsigned m = wave_min(v);
        if (m >= ownval && tid < 32) umax_l2(reps + tid * 16, m);
    }
}

// Subscriber wait (r15): own-replica poll + raw failsafe; optional inv.
__device__ __forceinline__ unsigned wait_ep(unsigned* reps, unsigned* raw, int n,
                                            unsigned T, int tid, int lrank,
                                            unsigned cached, bool do_inv,
                                            volatile unsigned* sh) {
    if (cached < T) {
        if (tid < 64) {
            unsigned* myrep = reps + lrank * 16;
            unsigned m = 0;
            long spin = 0;
            for (;;) {
                if ((spin & 7) == 7) {
                    unsigned v = (tid < n) ? rdflag_l2(raw + tid) : 0xFFFFFFFFu;
                    m = wave_min(v);
                } else {
                    if (tid == 0) m = rdflag_l2(myrep);
                    m = (unsigned)__shfl((int)m, 0);
                }
                if (m >= T) break;
                __builtin_amdgcn_s_sleep(1);
                if (++spin > (1L << 20)) break;   // failsafe
            }
            if (tid == 0) *sh = m;
        }
    }
    if (do_inv && tid == 0) inv_l1();
    __syncthreads();
    return (cached < T) ? *sh : cached;
}

// Cached raw wait (no epochs, no inv) — for L1's rarely-polled fP gate.
__device__ __forceinline__ unsigned wait_raw(unsigned* raw, int n, unsigned T,
                                             int tid, unsigned cached,
                                             volatile unsigned* sh) {
    if (cached < T) {
        if (tid < 64) {
            unsigned m;
            long spin = 0;
            for (;;) {
                unsigned v = (tid < n) ? rdflag_l2(raw + tid) : 0xFFFFFFFFu;
                m = wave_min(v);
                if (m >= T) break;
                __builtin_amdgcn_s_sleep(1);
                if (++spin > (1L << 20)) break;   // failsafe
            }
            if (tid == 0) *sh = m;
        }
    }
    __syncthreads();
    return (cached < T) ? *sh : cached;
}

// AGENT wait: r10 verbatim.
__device__ __forceinline__ void wait_agent(unsigned* f, int n, unsigned T,
                                           int tid, bool acquire) {
    if (tid < 64) {
        int l = tid < n ? tid : n - 1;
        long spin = 0;
        for (;;) {
            if (wave_min(ld_ag(f + l)) >= T) break;
            __builtin_amdgcn_s_sleep(1);
            if (++spin > (1L << 20)) break;
        }
    }
    if (acquire && tid == 0) acq_ag();
    __syncthreads();
}

#define DRAIN() do { asm volatile("s_waitcnt vmcnt(0)" ::: "memory"); __syncthreads(); } while (0)

// ---------------------------------------------------------------------------
template<bool LOCAL>
__device__ __forceinline__ void run_group(
    int group, int lrank, int tid, int lane, int w, int l15, int lk8,
    const float* __restrict__ x,
    const float* __restrict__ Wih1, const float* __restrict__ Whh1,
    const float* __restrict__ bih1, const float* __restrict__ bhh1,
    const float* __restrict__ Wih2, const float* __restrict__ Whh2,
    const float* __restrict__ bih2, const float* __restrict__ bhh2,
    const float* __restrict__ Wlin, const float* __restrict__ blin,
    float* __restrict__ out, unsigned char* __restrict__ gb,
    float (*red)[16][97], volatile unsigned* shm)
{
    unsigned* fL1  = (unsigned*)(gb + G_FL1);
    unsigned* fH2d = (unsigned*)(gb + G_FH2D);
    unsigned* fP   = (unsigned*)(gb + G_FP);
    unsigned* eL1  = (unsigned*)(gb + G_EL1);
    unsigned* eH2d = (unsigned*)(gb + G_EH2D);
    float*    Pb   = (float*)(gb + G_PB);      // [4][16][2][24]
    const int kb0 = w * 192;

    if (lrank < 8) {
        // ========================= L1 role ==================================
        const int c = lrank;
        const int col0 = c * 96;

        s16x8 whi[6][6], wlo[6][6];
#pragma unroll
        for (int ks = 0; ks < 6; ks++)
#pragma unroll
            for (int nt = 0; nt < 6; nt++)
                load_wfrag(Whh1, col0 + nt * 16 + l15, kb0 + ks * 32 + lk8,
                           whi[ks][nt], wlo[ks][nt]);

        const int er = tid >> 4;                // row 0..15
        const int ec0 = (tid & 15) * 6;         // 6 consecutive cols
        const int b = group * GROWS + er;
        float bs[6], wi0[6], wi1[6];
#pragma unroll
        for (int j = 0; j < 6; j++) {
            int cg = col0 + ec0 + j;
            bs[j] = bih1[cg] + bhh1[cg];
            wi0[j] = Wih1[cg * 2 + 0];
            wi1[j] = Wih1[cg * 2 + 1];
        }
        const int ov = tid >> 5;                // 0..3 (tid<128)
        const int oj = tid & 31;
        const int orow = 2 * c + (ov >> 1);
        const int ooo = ov & 1;
        const float blv = blin[ooo];

        unsigned fpc = 0, fl1c = 0;

        for (int t = 0; t < T_LEN; t++) {
            const int rs = (t + 3) & 3;         // h1(t-1) slot
            const int wsl = t & 3;              // h1(t) slot
            float x0 = x[b * 2048 + t];
            float x1 = x[b * 2048 + 1024 + t];

            // Top-of-iter off-path: fP gate (h1-slot guard + P reads).
            if (t >= 3) {
                if constexpr (LOCAL)
                    fpc = wait_raw(fP, 24, (unsigned)(t - 2), tid, fpc, &shm[0]);
                else
                    wait_agent(fP, 24, (unsigned)(t - 2), tid, false);
                if (tid < 128) {
                    float p = 0.f;
                    if (oj < 24)
                        p = __uint_as_float(rdp<LOCAL>((unsigned*)
                            (Pb + ((((t - 3) & 3) * 16 + orow) * 2 + ooo) * 24 + oj)));
#pragma unroll
                    for (int o = 16; o; o >>= 1) p += __shfl_down(p, o, 32);
                    if (oj == 0) out[(group * GROWS + orow) * 2048 + ooo * 1024 + (t - 3)] = p + blv;
                }
            }

            if (t) {
                if constexpr (LOCAL)
                    fl1c = wait_ep(eL1, fL1, 8, (unsigned)t, tid, lrank, fl1c, true, &shm[1]);
                else
                    wait_agent(fL1, 8, (unsigned)t, tid, true);
            }

            const unsigned short* Hh = (const unsigned short*)(gb + G_H1 + rs * 2 * HB_SZ);
            const unsigned short* Hl = (const unsigned short*)(gb + G_H1 + rs * 2 * HB_SZ + HB_SZ);
            s16x8 ah[6], al[6];
            ld6(Hh + l15 * H + kb0 + lk8, ah);
            ld6(Hl + l15 * H + kb0 + lk8, al);

            fx4 acc[6];
#pragma unroll
            for (int nt = 0; nt < 6; nt++) acc[nt] = fx4{0.f, 0.f, 0.f, 0.f};
#pragma unroll
            for (int ks = 0; ks < 6; ks++)
#pragma unroll
                for (int nt = 0; nt < 6; nt++) {
                    acc[nt] = mfma16(ah[ks], whi[ks][nt], acc[nt]);
                    acc[nt] = mfma16(ah[ks], wlo[ks][nt], acc[nt]);
                    acc[nt] = mfma16(al[ks], whi[ks][nt], acc[nt]);
                }

#pragma unroll
            for (int nt = 0; nt < 6; nt++)
#pragma unroll
                for (int i = 0; i < 4; i++)
                    red[w][(lane >> 4) * 4 + i][nt * 16 + l15] = acc[nt][i];
            __syncthreads();

            unsigned hw[3], lw[3];
#pragma unroll
            for (int jj = 0; jj < 3; jj++) {
                unsigned hp = 0, lp = 0;
#pragma unroll
                for (int k = 0; k < 2; k++) {
                    int j = jj * 2 + k;
                    int cc = ec0 + j;
                    float v = red[0][er][cc] + red[1][er][cc] + red[2][er][cc] + red[3][er][cc];
                    v += x0 * wi0[j] + x1 * wi1[j] + bs[j];
                    v = tanhf(v);
                    unsigned short hb = f2bf(v);
                    unsigned short lb = f2bf(v - bf2f(hb));
                    hp |= ((unsigned)hb) << (16 * k);
                    lp |= ((unsigned)lb) << (16 * k);
                }
                hw[jj] = hp; lw[jj] = lp;
            }

            unsigned* Dh = (unsigned*)(gb + G_H1 + wsl * 2 * HB_SZ) + ((long)er * H + col0 + ec0) / 2;
            unsigned* Dl = (unsigned*)(gb + G_H1 + wsl * 2 * HB_SZ + HB_SZ) + ((long)er * H + col0 + ec0) / 2;
            std32<LOCAL>(Dh + 0, hw[0]); std32<LOCAL>(Dh + 1, hw[1]); std32<LOCAL>(Dh + 2, hw[2]);
            std32<LOCAL>(Dl + 0, lw[0]); std32<LOCAL>(Dl + 1, lw[1]); std32<LOCAL>(Dl + 2, lw[2]);

            DRAIN();
            if constexpr (LOCAL)
                arrive_pub(fL1 + c, (unsigned)(t + 1), fL1, 8, c, eL1, tid);
            else if (tid == 0)
                st_ag(fL1 + c, (unsigned)(t + 1));
        }

        // tail: P(T-3..T-1) gated by fP >= T
        if constexpr (LOCAL)
            fpc = wait_raw(fP, 24, (unsigned)T_LEN, tid, fpc, &shm[0]);
        else
            wait_agent(fP, 24, (unsigned)T_LEN, tid, false);
        if (tid < 128) {
#pragma unroll
            for (int par = 0; par < 3; par++) {
                int tt = T_LEN - 3 + par;
                float p = 0.f;
                if (oj < 24)
                    p = __uint_as_float(rdp<LOCAL>((unsigned*)
                        (Pb + (((tt & 3) * 16 + orow) * 2 + ooo) * 24 + oj)));
#pragma unroll
                for (int o = 16; o; o >>= 1) p += __shfl_down(p, o, 32);
                if (oj == 0) out[(group * GROWS + orow) * 2048 + ooo * 1024 + tt] = p + blv;
            }
        }
    } else {
        // ========================= L2 role ==================================
        const int q = lrank - 8;         // 0..23
        const int col0 = q * 32;

        s16x8 ghi[2][6], glo[2][6], ihi[2][6], ilo[2][6];
#pragma unroll
        for (int nt = 0; nt < 2; nt++)
#pragma unroll
            for (int ks = 0; ks < 6; ks++) {
                load_wfrag(Whh2, col0 + nt * 16 + l15, kb0 + ks * 32 + lk8, ghi[nt][ks], glo[nt][ks]);
                load_wfrag(Wih2, col0 + nt * 16 + l15, kb0 + ks * 32 + lk8, ihi[nt][ks], ilo[nt][ks]);
            }

        const int er = tid >> 4;             // 0..15
        const int ec0 = (tid & 15) * 2;      // 0..30
        const float bsA = bih2[col0 + ec0] + bhh2[col0 + ec0];
        const float bsB = bih2[col0 + ec0 + 1] + bhh2[col0 + ec0 + 1];

        const int ro = tid >> 1, oo = tid & 1;   // tid<32
        float wl[32];
        if (tid < 32) {
#pragma unroll
            for (int cc = 0; cc < 32; cc++) wl[cc] = Wlin[oo * H + col0 + cc];
        }

        unsigned fh2c = 0, fl1c = 0;

        for (int t = 0; t < T_LEN; t++) {
            const int rb = (t + 1) & 1;     // h2(t-1) slot
            const int wb = t & 1;           // h2(t) slot
            const int hs = t & 3;           // h1(t) slot

            if (t) {
                if constexpr (LOCAL)
                    fh2c = wait_ep(eH2d, fH2d, 24, (unsigned)t, tid, lrank, fh2c, true, &shm[2]);
                else
                    wait_agent(fH2d, 24, (unsigned)t, tid, true);
            }

            const unsigned short* Gh = (const unsigned short*)(gb + G_H2 + rb * 2 * HB_SZ);
            const unsigned short* Gl = (const unsigned short*)(gb + G_H2 + rb * 2 * HB_SZ + HB_SZ);
            const unsigned short* Hh = (const unsigned short*)(gb + G_H1 + hs * 2 * HB_SZ);
            const unsigned short* Hl = (const unsigned short*)(gb + G_H1 + hs * 2 * HB_SZ + HB_SZ);

            s16x8 ah[6], al[6], bh[6], bl[6];
            bool h1rdy = false;
            if constexpr (LOCAL) h1rdy = (fl1c >= (unsigned)(t + 1));

            ld6(Gh + l15 * H + kb0 + lk8, ah);
            ld6(Gl + l15 * H + kb0 + lk8, al);
            if (h1rdy) {                      // prefetch h1 under phase1 MFMAs
                ld6(Hh + l15 * H + kb0 + lk8, bh);
                ld6(Hl + l15 * H + kb0 + lk8, bl);
            }

            fx4 a2[2];
            a2[0] = fx4{0.f, 0.f, 0.f, 0.f};
            a2[1] = fx4{0.f, 0.f, 0.f, 0.f};
#pragma unroll
            for (int ks = 0; ks < 6; ks++)
#pragma unroll
                for (int nt = 0; nt < 2; nt++) {
                    a2[nt] = mfma16(ah[ks], ghi[nt][ks], a2[nt]);
                    a2[nt] = mfma16(ah[ks], glo[nt][ks], a2[nt]);
                    a2[nt] = mfma16(al[ks], ghi[nt][ks], a2[nt]);
                }

            if (!h1rdy) {
                if constexpr (LOCAL)
                    fl1c = wait_ep(eL1, fL1, 8, (unsigned)(t + 1), tid, lrank, fl1c, false, &shm[3]);
                else
                    wait_agent(fL1, 8, (unsigned)(t + 1), tid, true);
                ld6(Hh + l15 * H + kb0 + lk8, bh);
                ld6(Hl + l15 * H + kb0 + lk8, bl);
            }

#pragma unroll
            for (int ks = 0; ks < 6; ks++)
#pragma unroll
                for (int nt = 0; nt < 2; nt++) {
                    a2[nt] = mfma16(bh[ks], ihi[nt][ks], a2[nt]);
                    a2[nt] = mfma16(bh[ks], ilo[nt][ks], a2[nt]);
                    a2[nt] = mfma16(bl[ks], ihi[nt][ks], a2[nt]);
                }

#pragma unroll
            for (int nt = 0; nt < 2; nt++)
#pragma unroll
                for (int i = 0; i < 4; i++)
                    red[w][(lane >> 4) * 4 + i][nt * 16 + l15] = a2[nt][i];
            __syncthreads();

            float v0 = red[0][er][ec0] + red[1][er][ec0] + red[2][er][ec0] + red[3][er][ec0] + bsA;
            float v1 = red[0][er][ec0 + 1] + red[1][er][ec0 + 1] + red[2][er][ec0 + 1] + red[3][er][ec0 + 1] + bsB;
            v0 = tanhf(v0); v1 = tanhf(v1);
            unsigned short hb0 = f2bf(v0), hb1 = f2bf(v1);
            unsigned hp = ((unsigned)hb0) | (((unsigned)hb1) << 16);
            unsigned lp = ((unsigned)f2bf(v0 - bf2f(hb0))) | (((unsigned)f2bf(v1 - bf2f(hb1))) << 16);
            unsigned* Dh = (unsigned*)(gb + G_H2 + wb * 2 * HB_SZ) + ((long)er * H + col0 + ec0) / 2;
            unsigned* Dl = (unsigned*)(gb + G_H2 + wb * 2 * HB_SZ + HB_SZ) + ((long)er * H + col0 + ec0) / 2;
            std32<LOCAL>(Dh, hp);
            std32<LOCAL>(Dl, lp);
            red[0][er][ec0] = v0;
            red[0][er][ec0 + 1] = v1;

            DRAIN();   // h2 stores committed + red[] visible
            if constexpr (LOCAL)
                arrive_pub(fH2d + q, (unsigned)(t + 1), fH2d, 24, q, eH2d, tid);
            else if (tid == 0)
                st_ag(fH2d + q, (unsigned)(t + 1));

            // off the h2 critical chain: out partial
            if (tid < 32) {
                float s = 0.f;
#pragma unroll
                for (int cc = 0; cc < 32; cc++) s += red[0][ro][cc] * wl[cc];
                std32<LOCAL>((unsigned*)&Pb[(((t & 3) * 16 + ro) * 2 + oo) * 24 + q],
                             __float_as_uint(s));
            }

            DRAIN();
            if (tid == 0) {
                if constexpr (LOCAL) stflag_l2(fP + q, (unsigned)(t + 1));
                else st_ag(fP + q, (unsigned)(t + 1));
            }
        }
    }
}

// ---------------------------------------------------------------------------
__global__ __launch_bounds__(256, 1) void rnn_persist(
    const float* __restrict__ x,
    const float* __restrict__ Wih1, const float* __restrict__ Whh1,
    const float* __restrict__ bih1, const float* __restrict__ bhh1,
    const float* __restrict__ Wih2, const float* __restrict__ Whh2,
    const float* __restrict__ bih2, const float* __restrict__ bhh2,
    const float* __restrict__ Wlin, const float* __restrict__ blin,
    float* __restrict__ out, unsigned char* __restrict__ ws)
{
    const int wg = blockIdx.x;
    const int tid = threadIdx.x;
    const int lane = tid & 63;
    const int w = tid >> 6;
    const int l15 = lane & 15;
    const int lk8 = (lane >> 4) * 8;

    __shared__ float red[4][16][97];
    __shared__ int iscr[256];
    __shared__ unsigned shm[4];

    // ---- runtime XCD discovery (agent scope, r5/r6/r12-proven) -------------
    unsigned* map = (unsigned*)(ws + MAP_OFF);
    unsigned* kbr = (unsigned*)(ws + KBR_OFF);

    int key;
    asm volatile("s_getreg_b32 %0, hwreg(HW_REG_XCC_ID, 0, 4)" : "=s"(key));
    key &= 0xF;

    if (tid == 0) st_ag(map + wg, (unsigned)(key + 1));
    unsigned kj;
    {
        long spin = 0;
        for (;;) {
            kj = ld_ag(map + tid);
            if (kj) break;
            __builtin_amdgcn_s_sleep(2);
            if (++spin > (1L << 20)) break;
        }
    }
    int contrib = (((int)kj - 1) < key || (((int)kj - 1) == key && tid < wg)) ? 1 : 0;
    iscr[tid] = contrib;
    __syncthreads();
#pragma unroll
    for (int s = 128; s; s >>= 1) {
        if (tid < s) iscr[tid] += iscr[tid + s];
        __syncthreads();
    }
    const int rank = iscr[0];
    __syncthreads();
    const int group = rank >> 5, lrank = rank & 31;

    if (tid == 0) st_ag(kbr + rank, (unsigned)(key + 1));
    unsigned kv;
    {
        long spin = 0;
        for (;;) {
            kv = ld_ag(kbr + tid);
            if (kv) break;
            __builtin_amdgcn_s_sleep(2);
            if (++spin > (1L << 20)) break;
        }
    }
    int eq = ((int)kv - 1 == key) ? 1 : 0;
    int bad = ((tid >> 5) == group && !eq) ? 1 : 0;
    iscr[tid] = eq | (bad << 16);
    __syncthreads();
#pragma unroll
    for (int s = 128; s; s >>= 1) {
        if (tid < s) iscr[tid] += iscr[tid + s];
        __syncthreads();
    }
    const int r0 = iscr[0];
    __syncthreads();
    const bool local = ((r0 & 0xFFFF) == 32) && ((r0 >> 16) == 0);

    unsigned char* gb = ws + GRP_BASE + (size_t)group * GRP_STRIDE;

    if (local)
        run_group<true>(group, lrank, tid, lane, w, l15, lk8,
                        x, Wih1, Whh1, bih1, bhh1, Wih2, Whh2, bih2, bhh2,
                        Wlin, blin, out, gb, red, shm);
    else
        run_group<false>(group, lrank, tid, lane, w, l15, lk8,
                         x, Wih1, Whh1, bih1, bhh1, Wih2, Whh2, bih2, bhh2,
                         Wlin, blin, out, gb, red, shm);
}

extern "C" void kernel_launch(void* const* d_in, const int* in_sizes, int n_in,
                              void* d_out, int out_size, void* d_ws, size_t ws_size,
                              hipStream_t stream) {
    const float* x    = (const float*)d_in[0];
    const float* Wih1 = (const float*)d_in[1];
    const float* Whh1 = (const float*)d_in[2];
    const float* bih1 = (const float*)d_in[3];
    const float* bhh1 = (const float*)d_in[4];
    const float* Wih2 = (const float*)d_in[5];
    const float* Whh2 = (const float*)d_in[6];
    const float* bih2 = (const float*)d_in[7];
    const float* bhh2 = (const float*)d_in[8];
    const float* Wlin = (const float*)d_in[9];
    const float* blin = (const float*)d_in[10];

    // Zero discovery tables, flags, epochs, h-state (initial h = 0).
    hipMemsetAsync(d_ws, 0, WS_TOTAL, stream);

    rnn_persist<<<NWG, 256, 0, stream>>>(x, Wih1, Whh1, bih1, bhh1,
                                         Wih2, Whh2, bih2, bhh2,
                                         Wlin, blin, (float*)d_out,
                                         (unsigned char*)d_ws);
}

// Round 18
// 6129.641 us; speedup vs baseline: 1.0953x; 1.0560x over previous
//
#include <hip/hip_runtime.h>
#include <math.h>

// ---------------------------------------------------------------------------
// 2-layer tanh RNN scan, B=128, T=1024, H=768.  Persistent kernel, 256 WGs.
// Round-18 = round-17 with DEEPER RINGS to decouple the L1/L2 chains:
//   * h1 ring 4->8 slots, P ring 4->8 slots.
//   * L1 out-reduce lag 3->7: gate fP >= t-6 (also covers h1-slot guard
//     fP >= t-7).  L1 runs up to 6 steps ahead of L2 -> L2's cached fL1
//     prefetch fast-path is the common case -> L2 critical cycle carries
//     ONE rendezvous (fH2d) + serve.
// Everything else r17 verbatim (proven): split fH2d/fP flags, epoch pub/sub
// (r15), one buffer_inv per L2 iter, sc0 stores -> XCD L2, plain L2-hit
// loads after inv, atomic P reads, bf16 hi/lo 3-product MFMA numerics,
// XCD discovery + AGENT fallback (r10) for non-co-resident groups.
// ---------------------------------------------------------------------------

typedef short s16x8 __attribute__((ext_vector_type(8)));
typedef float fx4   __attribute__((ext_vector_type(4)));

#define NWG    256
#define T_LEN  1024
#define H      768
#define GROUPS 8
#define GROWS  16

// ws layout (bytes)
#define MAP_OFF    0          // u32[256]
#define KBR_OFF    1024       // u32[256]
#define GRP_BASE   8192
#define G_FL1  0              // u32[8]
#define G_FH2D 128            // u32[24]
#define G_FP   256            // u32[24]
#define G_EL1  512            // 32 epoch replicas x 64B = 2048
#define G_EH2D 2560           // 32 epoch replicas x 64B = 2048
#define G_PB   4608           // float[8][16][2][24] = 24576B (ends 29184)
#define G_H1   29184          // 8 slots x {hi,lo} x 24576B (ends 422400)
#define G_H2   422400         // 2 slots x {hi,lo} x 24576B (ends 520704)
#define GRP_STRIDE 520704
#define HB_SZ 24576
#define WS_TOTAL (GRP_BASE + GROUPS * GRP_STRIDE)

__device__ __forceinline__ unsigned short f2bf(float x) {
    unsigned u = __float_as_uint(x);
    unsigned r = (u + 0x7FFFu + ((u >> 16) & 1u)) >> 16;   // RNE
    return (unsigned short)r;
}
__device__ __forceinline__ float bf2f(unsigned short b) {
    return __uint_as_float(((unsigned)b) << 16);
}
__device__ __forceinline__ fx4 mfma16(s16x8 a, s16x8 b, fx4 c) {
    return __builtin_amdgcn_mfma_f32_16x16x32_bf16(a, b, c, 0, 0, 0);
}

// ---- AGENT primitives (r10-proven) -----------------------------------------
__device__ __forceinline__ void st_ag(unsigned* p, unsigned v) {
    __hip_atomic_store(p, v, __ATOMIC_RELAXED, __HIP_MEMORY_SCOPE_AGENT);
}
__device__ __forceinline__ unsigned ld_ag(const unsigned* p) {
    return __hip_atomic_load(p, __ATOMIC_RELAXED, __HIP_MEMORY_SCOPE_AGENT);
}
__device__ __forceinline__ void acq_ag() {
    __builtin_amdgcn_fence(__ATOMIC_ACQUIRE, "agent");
}
// ---- LOCAL primitives (XCD-L2 scope; r12/r14/r15-proven) -------------------
__device__ __forceinline__ void st32_sc0(unsigned* p, unsigned v) {
    asm volatile("global_store_dword %0, %1, off sc0" :: "v"(p), "v"(v) : "memory");
}
__device__ __forceinline__ void stflag_l2(unsigned* p, unsigned v) {
    asm volatile("global_atomic_swap %0, %1, off" :: "v"(p), "v"(v) : "memory");
}
__device__ __forceinline__ void umax_l2(unsigned* p, unsigned v) {
    asm volatile("global_atomic_umax %0, %1, off" :: "v"(p), "v"(v) : "memory");
}
__device__ __forceinline__ unsigned rdflag_l2(unsigned* p) {
    unsigned v, z = 0;
    asm volatile("global_atomic_add %0, %1, %2, off sc0\n\ts_waitcnt vmcnt(0)"
                 : "=v"(v) : "v"(p), "v"(z) : "memory");
    return v;
}
__device__ __forceinline__ void inv_l1() {     // CU L1 invalidate (L2 intact)
    asm volatile("buffer_inv sc0" ::: "memory");
}

template<bool LOCAL> __device__ __forceinline__ unsigned rdp(unsigned* p) {
    if constexpr (LOCAL) return rdflag_l2(p); else return ld_ag(p);
}
template<bool LOCAL> __device__ __forceinline__ void std32(unsigned* p, unsigned v) {
    if constexpr (LOCAL) st32_sc0(p, v); else st_ag(p, v);
}

__device__ __forceinline__ void load_wfrag(const float* __restrict__ W,
                                           int col, int kk, s16x8& hi, s16x8& lo) {
    const float* p = W + (long)col * H + kk;
#pragma unroll
    for (int j = 0; j < 8; j++) {
        float w = p[j];
        unsigned short h = f2bf(w);
        float r = w - bf2f(h);
        hi[j] = (short)h;
        lo[j] = (short)f2bf(r);
    }
}

__device__ __forceinline__ void ld6(const unsigned short* p, s16x8 (&d)[6]) {
#pragma unroll
    for (int ks = 0; ks < 6; ks++)
        d[ks] = *reinterpret_cast<const s16x8*>(p + ks * 32);
}

__device__ __forceinline__ unsigned wave_min(unsigned v) {
#pragma unroll
    for (int o = 32; o; o >>= 1) {
        unsigned u = (unsigned)__shfl_xor((int)v, o);
        v = v < u ? v : u;
    }
    return v;
}

// r15 arrive + epoch publish: own swap; vmcnt; one raw poll round; publish
// min to 32 replicas iff min >= own value.
__device__ __forceinline__ void arrive_pub(unsigned* own, unsigned ownval,
                                           unsigned* raw, int n, int ownidx,
                                           unsigned* reps, int tid) {
    if (tid == 0) stflag_l2(own, ownval);
    if (tid < 64) {
        asm volatile("s_waitcnt vmcnt(0)" ::: "memory");
        unsigned v = 0xFFFFFFFFu;
        if (tid < n) v = (tid == ownidx) ? ownval : rdflag_l2(raw + tid);
        unsigned m = wave_min(v);
        if (m >= ownval && tid < 32) umax_l2(reps + tid * 16, m);
    }
}

// Subscriber wait (r15): own-replica poll + raw failsafe; optional inv.
__device__ __forceinline__ unsigned wait_ep(unsigned* reps, unsigned* raw, int n,
                                            unsigned T, int tid, int lrank,
                                            unsigned cached, bool do_inv,
                                            volatile unsigned* sh) {
    if (cached < T) {
        if (tid < 64) {
            unsigned* myrep = reps + lrank * 16;
            unsigned m = 0;
            long spin = 0;
            for (;;) {
                if ((spin & 7) == 7) {
                    unsigned v = (tid < n) ? rdflag_l2(raw + tid) : 0xFFFFFFFFu;
                    m = wave_min(v);
                } else {
                    if (tid == 0) m = rdflag_l2(myrep);
                    m = (unsigned)__shfl((int)m, 0);
                }
                if (m >= T) break;
                __builtin_amdgcn_s_sleep(1);
                if (++spin > (1L << 20)) break;   // failsafe
            }
            if (tid == 0) *sh = m;
        }
    }
    if (do_inv && tid == 0) inv_l1();
    __syncthreads();
    return (cached < T) ? *sh : cached;
}

// Cached raw wait (no epochs, no inv) — L1's rarely-polled fP gate.
__device__ __forceinline__ unsigned wait_raw(unsigned* raw, int n, unsigned T,
                                             int tid, unsigned cached,
                                             volatile unsigned* sh) {
    if (cached < T) {
        if (tid < 64) {
            unsigned m;
            long spin = 0;
            for (;;) {
                unsigned v = (tid < n) ? rdflag_l2(raw + tid) : 0xFFFFFFFFu;
                m = wave_min(v);
                if (m >= T) break;
                __builtin_amdgcn_s_sleep(1);
                if (++spin > (1L << 20)) break;   // failsafe
            }
            if (tid == 0) *sh = m;
        }
    }
    __syncthreads();
    return (cached < T) ? *sh : cached;
}

// AGENT wait: r10 verbatim.
__device__ __forceinline__ void wait_agent(unsigned* f, int n, unsigned T,
                                           int tid, bool acquire) {
    if (tid < 64) {
        int l = tid < n ? tid : n - 1;
        long spin = 0;
        for (;;) {
            if (wave_min(ld_ag(f + l)) >= T) break;
            __builtin_amdgcn_s_sleep(1);
            if (++spin > (1L << 20)) break;
        }
    }
    if (acquire && tid == 0) acq_ag();
    __syncthreads();
}

#define DRAIN() do { asm volatile("s_waitcnt vmcnt(0)" ::: "memory"); __syncthreads(); } while (0)

// ---------------------------------------------------------------------------
template<bool LOCAL>
__device__ __forceinline__ void run_group(
    int group, int lrank, int tid, int lane, int w, int l15, int lk8,
    const float* __restrict__ x,
    const float* __restrict__ Wih1, const float* __restrict__ Whh1,
    const float* __restrict__ bih1, const float* __restrict__ bhh1,
    const float* __restrict__ Wih2, const float* __restrict__ Whh2,
    const float* __restrict__ bih2, const float* __restrict__ bhh2,
    const float* __restrict__ Wlin, const float* __restrict__ blin,
    float* __restrict__ out, unsigned char* __restrict__ gb,
    float (*red)[16][97], volatile unsigned* shm)
{
    unsigned* fL1  = (unsigned*)(gb + G_FL1);
    unsigned* fH2d = (unsigned*)(gb + G_FH2D);
    unsigned* fP   = (unsigned*)(gb + G_FP);
    unsigned* eL1  = (unsigned*)(gb + G_EL1);
    unsigned* eH2d = (unsigned*)(gb + G_EH2D);
    float*    Pb   = (float*)(gb + G_PB);      // [8][16][2][24]
    const int kb0 = w * 192;

    if (lrank < 8) {
        // ========================= L1 role ==================================
        const int c = lrank;
        const int col0 = c * 96;

        s16x8 whi[6][6], wlo[6][6];
#pragma unroll
        for (int ks = 0; ks < 6; ks++)
#pragma unroll
            for (int nt = 0; nt < 6; nt++)
                load_wfrag(Whh1, col0 + nt * 16 + l15, kb0 + ks * 32 + lk8,
                           whi[ks][nt], wlo[ks][nt]);

        const int er = tid >> 4;                // row 0..15
        const int ec0 = (tid & 15) * 6;         // 6 consecutive cols
        const int b = group * GROWS + er;
        float bs[6], wi0[6], wi1[6];
#pragma unroll
        for (int j = 0; j < 6; j++) {
            int cg = col0 + ec0 + j;
            bs[j] = bih1[cg] + bhh1[cg];
            wi0[j] = Wih1[cg * 2 + 0];
            wi1[j] = Wih1[cg * 2 + 1];
        }
        const int ov = tid >> 5;                // 0..3 (tid<128)
        const int oj = tid & 31;
        const int orow = 2 * c + (ov >> 1);
        const int ooo = ov & 1;
        const float blv = blin[ooo];

        unsigned fpc = 0, fl1c = 0;

        for (int t = 0; t < T_LEN; t++) {
            const int rs = (t + 7) & 7;         // h1(t-1) slot
            const int wsl = t & 7;              // h1(t) slot
            float x0 = x[b * 2048 + t];
            float x1 = x[b * 2048 + 1024 + t];

            // Top-of-iter off-path: fP gate (h1-slot guard + out(t-7)).
            if (t >= 7) {
                if constexpr (LOCAL)
                    fpc = wait_raw(fP, 24, (unsigned)(t - 6), tid, fpc, &shm[0]);
                else
                    wait_agent(fP, 24, (unsigned)(t - 6), tid, false);
                if (tid < 128) {
                    float p = 0.f;
                    if (oj < 24)
                        p = __uint_as_float(rdp<LOCAL>((unsigned*)
                            (Pb + ((((t - 7) & 7) * 16 + orow) * 2 + ooo) * 24 + oj)));
#pragma unroll
                    for (int o = 16; o; o >>= 1) p += __shfl_down(p, o, 32);
                    if (oj == 0) out[(group * GROWS + orow) * 2048 + ooo * 1024 + (t - 7)] = p + blv;
                }
            }

            if (t) {
                if constexpr (LOCAL)
                    fl1c = wait_ep(eL1, fL1, 8, (unsigned)t, tid, lrank, fl1c, true, &shm[1]);
                else
                    wait_agent(fL1, 8, (unsigned)t, tid, true);
            }

            const unsigned short* Hh = (const unsigned short*)(gb + G_H1 + rs * 2 * HB_SZ);
            const unsigned short* Hl = (const unsigned short*)(gb + G_H1 + rs * 2 * HB_SZ + HB_SZ);
            s16x8 ah[6], al[6];
            ld6(Hh + l15 * H + kb0 + lk8, ah);
            ld6(Hl + l15 * H + kb0 + lk8, al);

            fx4 acc[6];
#pragma unroll
            for (int nt = 0; nt < 6; nt++) acc[nt] = fx4{0.f, 0.f, 0.f, 0.f};
#pragma unroll
            for (int ks = 0; ks < 6; ks++)
#pragma unroll
                for (int nt = 0; nt < 6; nt++) {
                    acc[nt] = mfma16(ah[ks], whi[ks][nt], acc[nt]);
                    acc[nt] = mfma16(ah[ks], wlo[ks][nt], acc[nt]);
                    acc[nt] = mfma16(al[ks], whi[ks][nt], acc[nt]);
                }

#pragma unroll
            for (int nt = 0; nt < 6; nt++)
#pragma unroll
                for (int i = 0; i < 4; i++)
                    red[w][(lane >> 4) * 4 + i][nt * 16 + l15] = acc[nt][i];
            __syncthreads();

            unsigned hw[3], lw[3];
#pragma unroll
            for (int jj = 0; jj < 3; jj++) {
                unsigned hp = 0, lp = 0;
#pragma unroll
                for (int k = 0; k < 2; k++) {
                    int j = jj * 2 + k;
                    int cc = ec0 + j;
                    float v = red[0][er][cc] + red[1][er][cc] + red[2][er][cc] + red[3][er][cc];
                    v += x0 * wi0[j] + x1 * wi1[j] + bs[j];
                    v = tanhf(v);
                    unsigned short hb = f2bf(v);
                    unsigned short lb = f2bf(v - bf2f(hb));
                    hp |= ((unsigned)hb) << (16 * k);
                    lp |= ((unsigned)lb) << (16 * k);
                }
                hw[jj] = hp; lw[jj] = lp;
            }

            unsigned* Dh = (unsigned*)(gb + G_H1 + wsl * 2 * HB_SZ) + ((long)er * H + col0 + ec0) / 2;
            unsigned* Dl = (unsigned*)(gb + G_H1 + wsl * 2 * HB_SZ + HB_SZ) + ((long)er * H + col0 + ec0) / 2;
            std32<LOCAL>(Dh + 0, hw[0]); std32<LOCAL>(Dh + 1, hw[1]); std32<LOCAL>(Dh + 2, hw[2]);
            std32<LOCAL>(Dl + 0, lw[0]); std32<LOCAL>(Dl + 1, lw[1]); std32<LOCAL>(Dl + 2, lw[2]);

            DRAIN();
            if constexpr (LOCAL)
                arrive_pub(fL1 + c, (unsigned)(t + 1), fL1, 8, c, eL1, tid);
            else if (tid == 0)
                st_ag(fL1 + c, (unsigned)(t + 1));
        }

        // tail: P(T-7..T-1) gated by fP >= T
        if constexpr (LOCAL)
            fpc = wait_raw(fP, 24, (unsigned)T_LEN, tid, fpc, &shm[0]);
        else
            wait_agent(fP, 24, (unsigned)T_LEN, tid, false);
        if (tid < 128) {
#pragma unroll
            for (int par = 0; par < 7; par++) {
                int tt = T_LEN - 7 + par;
                float p = 0.f;
                if (oj < 24)
                    p = __uint_as_float(rdp<LOCAL>((unsigned*)
                        (Pb + (((tt & 7) * 16 + orow) * 2 + ooo) * 24 + oj)));
#pragma unroll
                for (int o = 16; o; o >>= 1) p += __shfl_down(p, o, 32);
                if (oj == 0) out[(group * GROWS + orow) * 2048 + ooo * 1024 + tt] = p + blv;
            }
        }
    } else {
        // ========================= L2 role ==================================
        const int q = lrank - 8;         // 0..23
        const int col0 = q * 32;

        s16x8 ghi[2][6], glo[2][6], ihi[2][6], ilo[2][6];
#pragma unroll
        for (int nt = 0; nt < 2; nt++)
#pragma unroll
            for (int ks = 0; ks < 6; ks++) {
                load_wfrag(Whh2, col0 + nt * 16 + l15, kb0 + ks * 32 + lk8, ghi[nt][ks], glo[nt][ks]);
                load_wfrag(Wih2, col0 + nt * 16 + l15, kb0 + ks * 32 + lk8, ihi[nt][ks], ilo[nt][ks]);
            }

        const int er = tid >> 4;             // 0..15
        const int ec0 = (tid & 15) * 2;      // 0..30
        const float bsA = bih2[col0 + ec0] + bhh2[col0 + ec0];
        const float bsB = bih2[col0 + ec0 + 1] + bhh2[col0 + ec0 + 1];

        const int ro = tid >> 1, oo = tid & 1;   // tid<32
        float wl[32];
        if (tid < 32) {
#pragma unroll
            for (int cc = 0; cc < 32; cc++) wl[cc] = Wlin[oo * H + col0 + cc];
        }

        unsigned fh2c = 0, fl1c = 0;

        for (int t = 0; t < T_LEN; t++) {
            const int rb = (t + 1) & 1;     // h2(t-1) slot
            const int wb = t & 1;           // h2(t) slot
            const int hs = t & 7;           // h1(t) slot

            if (t) {
                if constexpr (LOCAL)
                    fh2c = wait_ep(eH2d, fH2d, 24, (unsigned)t, tid, lrank, fh2c, true, &shm[2]);
                else
                    wait_agent(fH2d, 24, (unsigned)t, tid, true);
            }

            const unsigned short* Gh = (const unsigned short*)(gb + G_H2 + rb * 2 * HB_SZ);
            const unsigned short* Gl = (const unsigned short*)(gb + G_H2 + rb * 2 * HB_SZ + HB_SZ);
            const unsigned short* Hh = (const unsigned short*)(gb + G_H1 + hs * 2 * HB_SZ);
            const unsigned short* Hl = (const unsigned short*)(gb + G_H1 + hs * 2 * HB_SZ + HB_SZ);

            s16x8 ah[6], al[6], bh[6], bl[6];
            bool h1rdy = false;
            if constexpr (LOCAL) h1rdy = (fl1c >= (unsigned)(t + 1));

            ld6(Gh + l15 * H + kb0 + lk8, ah);
            ld6(Gl + l15 * H + kb0 + lk8, al);
            if (h1rdy) {                      // prefetch h1 under phase1 MFMAs
                ld6(Hh + l15 * H + kb0 + lk8, bh);
                ld6(Hl + l15 * H + kb0 + lk8, bl);
            }

            fx4 a2[2];
            a2[0] = fx4{0.f, 0.f, 0.f, 0.f};
            a2[1] = fx4{0.f, 0.f, 0.f, 0.f};
#pragma unroll
            for (int ks = 0; ks < 6; ks++)
#pragma unroll
                for (int nt = 0; nt < 2; nt++) {
                    a2[nt] = mfma16(ah[ks], ghi[nt][ks], a2[nt]);
                    a2[nt] = mfma16(ah[ks], glo[nt][ks], a2[nt]);
                    a2[nt] = mfma16(al[ks], ghi[nt][ks], a2[nt]);
                }

            if (!h1rdy) {
                if constexpr (LOCAL)
                    fl1c = wait_ep(eL1, fL1, 8, (unsigned)(t + 1), tid, lrank, fl1c, false, &shm[3]);
                else
                    wait_agent(fL1, 8, (unsigned)(t + 1), tid, true);
                ld6(Hh + l15 * H + kb0 + lk8, bh);
                ld6(Hl + l15 * H + kb0 + lk8, bl);
            }

#pragma unroll
            for (int ks = 0; ks < 6; ks++)
#pragma unroll
                for (int nt = 0; nt < 2; nt++) {
                    a2[nt] = mfma16(bh[ks], ihi[nt][ks], a2[nt]);
                    a2[nt] = mfma16(bh[ks], ilo[nt][ks], a2[nt]);
                    a2[nt] = mfma16(bl[ks], ihi[nt][ks], a2[nt]);
                }

#pragma unroll
            for (int nt = 0; nt < 2; nt++)
#pragma unroll
                for (int i = 0; i < 4; i++)
                    red[w][(lane >> 4) * 4 + i][nt * 16 + l15] = a2[nt][i];
            __syncthreads();

            float v0 = red[0][er][ec0] + red[1][er][ec0] + red[2][er][ec0] + red[3][er][ec0] + bsA;
            float v1 = red[0][er][ec0 + 1] + red[1][er][ec0 + 1] + red[2][er][ec0 + 1] + red[3][er][ec0 + 1] + bsB;
            v0 = tanhf(v0); v1 = tanhf(v1);
            unsigned short hb0 = f2bf(v0), hb1 = f2bf(v1);
            unsigned hp = ((unsigned)hb0) | (((unsigned)hb1) << 16);
            unsigned lp = ((unsigned)f2bf(v0 - bf2f(hb0))) | (((unsigned)f2bf(v1 - bf2f(hb1))) << 16);
            unsigned* Dh = (unsigned*)(gb + G_H2 + wb * 2 * HB_SZ) + ((long)er * H + col0 + ec0) / 2;
            unsigned* Dl = (unsigned*)(gb + G_H2 + wb * 2 * HB_SZ + HB_SZ) + ((long)er * H + col0 + ec0) / 2;
            std32<LOCAL>(Dh, hp);
            std32<LOCAL>(Dl, lp);
            red[0][er][ec0] = v0;
            red[0][er][ec0 + 1] = v1;

            DRAIN();   // h2 stores committed + red[] visible
            if constexpr (LOCAL)
                arrive_pub(fH2d + q, (unsigned)(t + 1), fH2d, 24, q, eH2d, tid);
            else if (tid == 0)
                st_ag(fH2d + q, (unsigned)(t + 1));

            // off the h2 critical chain: out partial
            if (tid < 32) {
                float s = 0.f;
#pragma unroll
                for (int cc = 0; cc < 32; cc++) s += red[0][ro][cc] * wl[cc];
                std32<LOCAL>((unsigned*)&Pb[(((t & 7) * 16 + ro) * 2 + oo) * 24 + q],
                             __float_as_uint(s));
            }

            DRAIN();
            if (tid == 0) {
                if constexpr (LOCAL) stflag_l2(fP + q, (unsigned)(t + 1));
                else st_ag(fP + q, (unsigned)(t + 1));
            }
        }
    }
}

// ---------------------------------------------------------------------------
__global__ __launch_bounds__(256, 1) void rnn_persist(
    const float* __restrict__ x,
    const float* __restrict__ Wih1, const float* __restrict__ Whh1,
    const float* __restrict__ bih1, const float* __restrict__ bhh1,
    const float* __restrict__ Wih2, const float* __restrict__ Whh2,
    const float* __restrict__ bih2, const float* __restrict__ bhh2,
    const float* __restrict__ Wlin, const float* __restrict__ blin,
    float* __restrict__ out, unsigned char* __restrict__ ws)
{
    const int wg = blockIdx.x;
    const int tid = threadIdx.x;
    const int lane = tid & 63;
    const int w = tid >> 6;
    const int l15 = lane & 15;
    const int lk8 = (lane >> 4) * 8;

    __shared__ float red[4][16][97];
    __shared__ int iscr[256];
    __shared__ unsigned shm[4];

    // ---- runtime XCD discovery (agent scope, r5/r6/r12-proven) -------------
    unsigned* map = (unsigned*)(ws + MAP_OFF);
    unsigned* kbr = (unsigned*)(ws + KBR_OFF);

    int key;
    asm volatile("s_getreg_b32 %0, hwreg(HW_REG_XCC_ID, 0, 4)" : "=s"(key));
    key &= 0xF;

    if (tid == 0) st_ag(map + wg, (unsigned)(key + 1));
    unsigned kj;
    {
        long spin = 0;
        for (;;) {
            kj = ld_ag(map + tid);
            if (kj) break;
            __builtin_amdgcn_s_sleep(2);
            if (++spin > (1L << 20)) break;
        }
    }
    int contrib = (((int)kj - 1) < key || (((int)kj - 1) == key && tid < wg)) ? 1 : 0;
    iscr[tid] = contrib;
    __syncthreads();
#pragma unroll
    for (int s = 128; s; s >>= 1) {
        if (tid < s) iscr[tid] += iscr[tid + s];
        __syncthreads();
    }
    const int rank = iscr[0];
    __syncthreads();
    const int group = rank >> 5, lrank = rank & 31;

    if (tid == 0) st_ag(kbr + rank, (unsigned)(key + 1));
    unsigned kv;
    {
        long spin = 0;
        for (;;) {
            kv = ld_ag(kbr + tid);
            if (kv) break;
            __builtin_amdgcn_s_sleep(2);
            if (++spin > (1L << 20)) break;
        }
    }
    int eq = ((int)kv - 1 == key) ? 1 : 0;
    int bad = ((tid >> 5) == group && !eq) ? 1 : 0;
    iscr[tid] = eq | (bad << 16);
    __syncthreads();
#pragma unroll
    for (int s = 128; s; s >>= 1) {
        if (tid < s) iscr[tid] += iscr[tid + s];
        __syncthreads();
    }
    const int r0 = iscr[0];
    __syncthreads();
    const bool local = ((r0 & 0xFFFF) == 32) && ((r0 >> 16) == 0);

    unsigned char* gb = ws + GRP_BASE + (size_t)group * GRP_STRIDE;

    if (local)
        run_group<true>(group, lrank, tid, lane, w, l15, lk8,
                        x, Wih1, Whh1, bih1, bhh1, Wih2, Whh2, bih2, bhh2,
                        Wlin, blin, out, gb, red, shm);
    else
        run_group<false>(group, lrank, tid, lane, w, l15, lk8,
                         x, Wih1, Whh1, bih1, bhh1, Wih2, Whh2, bih2, bhh2,
                         Wlin, blin, out, gb, red, shm);
}

extern "C" void kernel_launch(void* const* d_in, const int* in_sizes, int n_in,
                              void* d_out, int out_size, void* d_ws, size_t ws_size,
                              hipStream_t stream) {
    const float* x    = (const float*)d_in[0];
    const float* Wih1 = (const float*)d_in[1];
    const float* Whh1 = (const float*)d_in[2];
    const float* bih1 = (const float*)d_in[3];
    const float* bhh1 = (const float*)d_in[4];
    const float* Wih2 = (const float*)d_in[5];
    const float* Whh2 = (const float*)d_in[6];
    const float* bih2 = (const float*)d_in[7];
    const float* bhh2 = (const float*)d_in[8];
    const float* Wlin = (const float*)d_in[9];
    const float* blin = (const float*)d_in[10];

    // Zero discovery tables, flags, epochs, h-state (initial h = 0).
    hipMemsetAsync(d_ws, 0, WS_TOTAL, stream);

    rnn_persist<<<NWG, 256, 0, stream>>>(x, Wih1, Whh1, bih1, bhh1,
                                         Wih2, Whh2, bih2, bhh2,
                                         Wlin, blin, (float*)d_out,
                                         (unsigned char*)d_ws);
}

// Round 19
// 5222.587 us; speedup vs baseline: 1.2855x; 1.1737x over previous
//
#include <hip/hip_runtime.h>
#include <math.h>

// ---------------------------------------------------------------------------
// 2-layer tanh RNN scan, B=128, T=1024, H=768.  Persistent kernel, 256 WGs.
// Round-19 = round-18 with PER-WAVE fine-grained rendezvous:
//   * wave w consumes h2 cols from exactly 6 L2 WGs and h1 cols from exactly
//     2 L1 WGs -> it polls ONLY those flags (no syncthreads, no broadcast)
//     and starts its loads/MFMAs as soon as ITS producers are done.
//   * anti-deps stay closed by the UNION argument: the 4 waves poll disjoint
//     flag slices, so at the existing LDS-reduce __syncthreads() the WG has
//     collectively verified min over ALL flags >= T; all stores (h2/h1/P)
//     happen after that barrier.  (Each edge re-audited.)
//   * one unconditional buffer_inv per wave per iter before h-loads (slots
//     alias every 2-8 steps; cached waits skip polls but not the inv).
//   * flags padded to 64B stride (atomic polls spread across lines); epoch
//     pub/sub machinery deleted (obsolete at 6/2 fan-in).
//   * L1's fP gate: skip entirely (incl. syncthreads) when cached.
// Data path & numerics r12/r14-proven: sc0 stores -> XCD L2; plain L2-hit
// loads after inv; atomic P reads; 8-slot h1 / 2-slot h2 / 8-slot P rings;
// bf16 hi/lo 3-product MFMA; XCD discovery + AGENT fallback (r10).
// ---------------------------------------------------------------------------

typedef short s16x8 __attribute__((ext_vector_type(8)));
typedef float fx4   __attribute__((ext_vector_type(4)));

#define NWG    256
#define T_LEN  1024
#define H      768
#define GROUPS 8
#define GROWS  16

// ws layout (bytes); flags padded to 64B stride (16 u32)
#define MAP_OFF    0          // u32[256]
#define KBR_OFF    1024       // u32[256]
#define GRP_BASE   8192
#define G_FL1  0              // 8  x 64B = 512
#define G_FH2D 512            // 24 x 64B = 1536 (ends 2048)
#define G_FP   2048           // 24 x 64B = 1536 (ends 3584)
#define G_PB   3584           // float[8][16][2][24] = 24576 (ends 28160)
#define G_H1   28160          // 8 slots x {hi,lo} x 24576 (ends 421376)
#define G_H2   421376         // 2 slots x {hi,lo} x 24576 (ends 519680)
#define GRP_STRIDE 520704
#define HB_SZ 24576
#define WS_TOTAL (GRP_BASE + GROUPS * GRP_STRIDE)

__device__ __forceinline__ unsigned short f2bf(float x) {
    unsigned u = __float_as_uint(x);
    unsigned r = (u + 0x7FFFu + ((u >> 16) & 1u)) >> 16;   // RNE
    return (unsigned short)r;
}
__device__ __forceinline__ float bf2f(unsigned short b) {
    return __uint_as_float(((unsigned)b) << 16);
}
__device__ __forceinline__ fx4 mfma16(s16x8 a, s16x8 b, fx4 c) {
    return __builtin_amdgcn_mfma_f32_16x16x32_bf16(a, b, c, 0, 0, 0);
}

// ---- AGENT primitives (r10-proven) -----------------------------------------
__device__ __forceinline__ void st_ag(unsigned* p, unsigned v) {
    __hip_atomic_store(p, v, __ATOMIC_RELAXED, __HIP_MEMORY_SCOPE_AGENT);
}
__device__ __forceinline__ unsigned ld_ag(const unsigned* p) {
    return __hip_atomic_load(p, __ATOMIC_RELAXED, __HIP_MEMORY_SCOPE_AGENT);
}
__device__ __forceinline__ void acq_ag() {
    __builtin_amdgcn_fence(__ATOMIC_ACQUIRE, "agent");
}
// ---- LOCAL primitives (XCD-L2 scope; r12/r14-proven) -----------------------
__device__ __forceinline__ void st32_sc0(unsigned* p, unsigned v) {
    asm volatile("global_store_dword %0, %1, off sc0" :: "v"(p), "v"(v) : "memory");
}
__device__ __forceinline__ void stflag_l2(unsigned* p, unsigned v) {
    asm volatile("global_atomic_swap %0, %1, off" :: "v"(p), "v"(v) : "memory");
}
__device__ __forceinline__ unsigned rdflag_l2(unsigned* p) {
    unsigned v, z = 0;
    asm volatile("global_atomic_add %0, %1, %2, off sc0\n\ts_waitcnt vmcnt(0)"
                 : "=v"(v) : "v"(p), "v"(z) : "memory");
    return v;
}
__device__ __forceinline__ void inv_l1() {     // CU L1 invalidate (L2 intact)
    asm volatile("buffer_inv sc0" ::: "memory");
}

template<bool LOCAL> __device__ __forceinline__ unsigned rdp(unsigned* p) {
    if constexpr (LOCAL) return rdflag_l2(p); else return ld_ag(p);
}
template<bool LOCAL> __device__ __forceinline__ void std32(unsigned* p, unsigned v) {
    if constexpr (LOCAL) st32_sc0(p, v); else st_ag(p, v);
}

__device__ __forceinline__ void load_wfrag(const float* __restrict__ W,
                                           int col, int kk, s16x8& hi, s16x8& lo) {
    const float* p = W + (long)col * H + kk;
#pragma unroll
    for (int j = 0; j < 8; j++) {
        float w = p[j];
        unsigned short h = f2bf(w);
        float r = w - bf2f(h);
        hi[j] = (short)h;
        lo[j] = (short)f2bf(r);
    }
}

__device__ __forceinline__ void ld6(const unsigned short* p, s16x8 (&d)[6]) {
#pragma unroll
    for (int ks = 0; ks < 6; ks++)
        d[ks] = *reinterpret_cast<const s16x8*>(p + ks * 32);
}

__device__ __forceinline__ unsigned wave_min(unsigned v) {
#pragma unroll
    for (int o = 32; o; o >>= 1) {
        unsigned u = (unsigned)__shfl_xor((int)v, o);
        v = v < u ? v : u;
    }
    return v;
}

// LOCAL per-wave wait: lanes 0..n-1 poll padded flags f[lane*16]; no barrier,
// no inv.  Cached-skip.  Returns observed slice-min (wave-uniform).
__device__ __forceinline__ unsigned wait_wv(unsigned* f, int n, unsigned T,
                                            int lane, unsigned cached) {
    if (cached >= T) return cached;
    unsigned m;
    long spin = 0;
    for (;;) {
        unsigned v = (lane < n) ? rdflag_l2(f + lane * 16) : 0xFFFFFFFFu;
        m = wave_min(v);
        if (m >= T) break;
        __builtin_amdgcn_s_sleep(1);
        if (++spin > (1L << 20)) break;   // failsafe
    }
    return m;
}

// LOCAL whole-WG gate (L1's fP): cached-skip WITHOUT syncthreads; on poll,
// wave 0 polls padded flags, broadcast, syncthreads.
__device__ __forceinline__ unsigned gate_raw(unsigned* raw, int n, unsigned T,
                                             int tid, unsigned cached,
                                             volatile unsigned* sh) {
    if (cached >= T) return cached;
    if (tid < 64) {
        unsigned m;
        long spin = 0;
        for (;;) {
            unsigned v = (tid < n) ? rdflag_l2(raw + tid * 16) : 0xFFFFFFFFu;
            m = wave_min(v);
            if (m >= T) break;
            __builtin_amdgcn_s_sleep(1);
            if (++spin > (1L << 20)) break;   // failsafe
        }
        if (tid == 0) *sh = m;
    }
    __syncthreads();
    return *sh;
}

// AGENT whole-WG wait on padded flags (r10 mechanics).
__device__ __forceinline__ void wait_agent(unsigned* f, int n, unsigned T,
                                           int tid, bool acquire) {
    if (tid < 64) {
        int l = tid < n ? tid : n - 1;
        long spin = 0;
        for (;;) {
            if (wave_min(ld_ag(f + l * 16)) >= T) break;
            __builtin_amdgcn_s_sleep(1);
            if (++spin > (1L << 20)) break;
        }
    }
    if (acquire && tid == 0) acq_ag();
    __syncthreads();
}

#define DRAIN() do { asm volatile("s_waitcnt vmcnt(0)" ::: "memory"); __syncthreads(); } while (0)

// ---------------------------------------------------------------------------
template<bool LOCAL>
__device__ __forceinline__ void run_group(
    int group, int lrank, int tid, int lane, int w, int l15, int lk8,
    const float* __restrict__ x,
    const float* __restrict__ Wih1, const float* __restrict__ Whh1,
    const float* __restrict__ bih1, const float* __restrict__ bhh1,
    const float* __restrict__ Wih2, const float* __restrict__ Whh2,
    const float* __restrict__ bih2, const float* __restrict__ bhh2,
    const float* __restrict__ Wlin, const float* __restrict__ blin,
    float* __restrict__ out, unsigned char* __restrict__ gb,
    float (*red)[16][97], volatile unsigned* shm)
{
    unsigned* fL1  = (unsigned*)(gb + G_FL1);
    unsigned* fH2d = (unsigned*)(gb + G_FH2D);
    unsigned* fP   = (unsigned*)(gb + G_FP);
    float*    Pb   = (float*)(gb + G_PB);      // [8][16][2][24]
    const int kb0 = w * 192;

    if (lrank < 8) {
        // ========================= L1 role ==================================
        const int c = lrank;
        const int col0 = c * 96;

        s16x8 whi[6][6], wlo[6][6];
#pragma unroll
        for (int ks = 0; ks < 6; ks++)
#pragma unroll
            for (int nt = 0; nt < 6; nt++)
                load_wfrag(Whh1, col0 + nt * 16 + l15, kb0 + ks * 32 + lk8,
                           whi[ks][nt], wlo[ks][nt]);

        const int er = tid >> 4;                // row 0..15
        const int ec0 = (tid & 15) * 6;         // 6 consecutive cols
        const int b = group * GROWS + er;
        float bs[6], wi0[6], wi1[6];
#pragma unroll
        for (int j = 0; j < 6; j++) {
            int cg = col0 + ec0 + j;
            bs[j] = bih1[cg] + bhh1[cg];
            wi0[j] = Wih1[cg * 2 + 0];
            wi1[j] = Wih1[cg * 2 + 1];
        }
        const int ov = tid >> 5;                // 0..3 (tid<128)
        const int oj = tid & 31;
        const int orow = 2 * c + (ov >> 1);
        const int ooo = ov & 1;
        const float blv = blin[ooo];

        unsigned fpc = 0;
        unsigned fl1w = 0;                      // per-wave cached fL1 slice min

        for (int t = 0; t < T_LEN; t++) {
            const int rs = (t + 7) & 7;         // h1(t-1) slot
            const int wsl = t & 7;              // h1(t) slot
            float x0 = x[b * 2048 + t];
            float x1 = x[b * 2048 + 1024 + t];

            // Off-path: fP gate (h1-slot guard + out(t-7)); skip-if-cached.
            if (t >= 7) {
                if constexpr (LOCAL)
                    fpc = gate_raw(fP, 24, (unsigned)(t - 6), tid, fpc, &shm[0]);
                else
                    wait_agent(fP, 24, (unsigned)(t - 6), tid, false);
                if (tid < 128) {
                    float p = 0.f;
                    if (oj < 24)
                        p = __uint_as_float(rdp<LOCAL>((unsigned*)
                            (Pb + ((((t - 7) & 7) * 16 + orow) * 2 + ooo) * 24 + oj)));
#pragma unroll
                    for (int o = 16; o; o >>= 1) p += __shfl_down(p, o, 32);
                    if (oj == 0) out[(group * GROWS + orow) * 2048 + ooo * 1024 + (t - 7)] = p + blv;
                }
            }

            // Per-wave true-dep wait: my 2 producers of K-slice of h1(t-1).
            if (t) {
                if constexpr (LOCAL) {
                    fl1w = wait_wv(fL1 + 2 * w * 16, 2, (unsigned)t, lane, fl1w);
                    inv_l1();
                } else {
                    wait_agent(fL1, 8, (unsigned)t, tid, true);
                }
            }

            const unsigned short* Hh = (const unsigned short*)(gb + G_H1 + rs * 2 * HB_SZ);
            const unsigned short* Hl = (const unsigned short*)(gb + G_H1 + rs * 2 * HB_SZ + HB_SZ);
            s16x8 ah[6], al[6];
            ld6(Hh + l15 * H + kb0 + lk8, ah);
            ld6(Hl + l15 * H + kb0 + lk8, al);

            fx4 acc[6];
#pragma unroll
            for (int nt = 0; nt < 6; nt++) acc[nt] = fx4{0.f, 0.f, 0.f, 0.f};
#pragma unroll
            for (int ks = 0; ks < 6; ks++)
#pragma unroll
                for (int nt = 0; nt < 6; nt++) {
                    acc[nt] = mfma16(ah[ks], whi[ks][nt], acc[nt]);
                    acc[nt] = mfma16(ah[ks], wlo[ks][nt], acc[nt]);
                    acc[nt] = mfma16(al[ks], whi[ks][nt], acc[nt]);
                }

#pragma unroll
            for (int nt = 0; nt < 6; nt++)
#pragma unroll
                for (int i = 0; i < 4; i++)
                    red[w][(lane >> 4) * 4 + i][nt * 16 + l15] = acc[nt][i];
            __syncthreads();   // full join: union of per-wave waits => all fL1 >= t

            unsigned hw[3], lw[3];
#pragma unroll
            for (int jj = 0; jj < 3; jj++) {
                unsigned hp = 0, lp = 0;
#pragma unroll
                for (int k = 0; k < 2; k++) {
                    int j = jj * 2 + k;
                    int cc = ec0 + j;
                    float v = red[0][er][cc] + red[1][er][cc] + red[2][er][cc] + red[3][er][cc];
                    v += x0 * wi0[j] + x1 * wi1[j] + bs[j];
                    v = tanhf(v);
                    unsigned short hb = f2bf(v);
                    unsigned short lb = f2bf(v - bf2f(hb));
                    hp |= ((unsigned)hb) << (16 * k);
                    lp |= ((unsigned)lb) << (16 * k);
                }
                hw[jj] = hp; lw[jj] = lp;
            }

            unsigned* Dh = (unsigned*)(gb + G_H1 + wsl * 2 * HB_SZ) + ((long)er * H + col0 + ec0) / 2;
            unsigned* Dl = (unsigned*)(gb + G_H1 + wsl * 2 * HB_SZ + HB_SZ) + ((long)er * H + col0 + ec0) / 2;
            std32<LOCAL>(Dh + 0, hw[0]); std32<LOCAL>(Dh + 1, hw[1]); std32<LOCAL>(Dh + 2, hw[2]);
            std32<LOCAL>(Dl + 0, lw[0]); std32<LOCAL>(Dl + 1, lw[1]); std32<LOCAL>(Dl + 2, lw[2]);

            DRAIN();
            if (tid == 0) {
                if constexpr (LOCAL) stflag_l2(fL1 + c * 16, (unsigned)(t + 1));
                else st_ag(fL1 + c * 16, (unsigned)(t + 1));
            }
        }

        // tail: P(T-7..T-1) gated by fP >= T
        if constexpr (LOCAL)
            fpc = gate_raw(fP, 24, (unsigned)T_LEN, tid, fpc, &shm[0]);
        else
            wait_agent(fP, 24, (unsigned)T_LEN, tid, false);
        if (tid < 128) {
#pragma unroll
            for (int par = 0; par < 7; par++) {
                int tt = T_LEN - 7 + par;
                float p = 0.f;
                if (oj < 24)
                    p = __uint_as_float(rdp<LOCAL>((unsigned*)
                        (Pb + (((tt & 7) * 16 + orow) * 2 + ooo) * 24 + oj)));
#pragma unroll
                for (int o = 16; o; o >>= 1) p += __shfl_down(p, o, 32);
                if (oj == 0) out[(group * GROWS + orow) * 2048 + ooo * 1024 + tt] = p + blv;
            }
        }
    } else {
        // ========================= L2 role ==================================
        const int q = lrank - 8;         // 0..23
        const int col0 = q * 32;

        s16x8 ghi[2][6], glo[2][6], ihi[2][6], ilo[2][6];
#pragma unroll
        for (int nt = 0; nt < 2; nt++)
#pragma unroll
            for (int ks = 0; ks < 6; ks++) {
                load_wfrag(Whh2, col0 + nt * 16 + l15, kb0 + ks * 32 + lk8, ghi[nt][ks], glo[nt][ks]);
                load_wfrag(Wih2, col0 + nt * 16 + l15, kb0 + ks * 32 + lk8, ihi[nt][ks], ilo[nt][ks]);
            }

        const int er = tid >> 4;             // 0..15
        const int ec0 = (tid & 15) * 2;      // 0..30
        const float bsA = bih2[col0 + ec0] + bhh2[col0 + ec0];
        const float bsB = bih2[col0 + ec0 + 1] + bhh2[col0 + ec0 + 1];

        const int ro = tid >> 1, oo = tid & 1;   // tid<32
        float wl[32];
        if (tid < 32) {
#pragma unroll
            for (int cc = 0; cc < 32; cc++) wl[cc] = Wlin[oo * H + col0 + cc];
        }

        unsigned fh2w = 0, fl1w = 0;         // per-wave cached slice mins

        for (int t = 0; t < T_LEN; t++) {
            const int rb = (t + 1) & 1;     // h2(t-1) slot
            const int wb = t & 1;           // h2(t) slot
            const int hs = t & 7;           // h1(t) slot

            // Per-wave true-dep wait: my 6 producers of K-slice of h2(t-1).
            if (t) {
                if constexpr (LOCAL)
                    fh2w = wait_wv(fH2d + 6 * w * 16, 6, (unsigned)t, lane, fh2w);
                else
                    wait_agent(fH2d, 24, (unsigned)t, tid, true);
            }
            bool h1rdy = false;
            if constexpr (LOCAL) {
                inv_l1();                   // acquire for this iter's loads
                h1rdy = (fl1w >= (unsigned)(t + 1));
            }

            const unsigned short* Gh = (const unsigned short*)(gb + G_H2 + rb * 2 * HB_SZ);
            const unsigned short* Gl = (const unsigned short*)(gb + G_H2 + rb * 2 * HB_SZ + HB_SZ);
            const unsigned short* Hh = (const unsigned short*)(gb + G_H1 + hs * 2 * HB_SZ);
            const unsigned short* Hl = (const unsigned short*)(gb + G_H1 + hs * 2 * HB_SZ + HB_SZ);

            s16x8 ah[6], al[6], bh[6], bl[6];
            ld6(Gh + l15 * H + kb0 + lk8, ah);
            ld6(Gl + l15 * H + kb0 + lk8, al);
            if (h1rdy) {                      // prefetch h1 under phase1 MFMAs
                ld6(Hh + l15 * H + kb0 + lk8, bh);
                ld6(Hl + l15 * H + kb0 + lk8, bl);
            }

            fx4 a2[2];
            a2[0] = fx4{0.f, 0.f, 0.f, 0.f};
            a2[1] = fx4{0.f, 0.f, 0.f, 0.f};
#pragma unroll
            for (int ks = 0; ks < 6; ks++)
#pragma unroll
                for (int nt = 0; nt < 2; nt++) {
                    a2[nt] = mfma16(ah[ks], ghi[nt][ks], a2[nt]);
                    a2[nt] = mfma16(ah[ks], glo[nt][ks], a2[nt]);
                    a2[nt] = mfma16(al[ks], ghi[nt][ks], a2[nt]);
                }

            if (!h1rdy) {
                if constexpr (LOCAL) {
                    fl1w = wait_wv(fL1 + 2 * w * 16, 2, (unsigned)(t + 1), lane, fl1w);
                    // no inv needed: h1 lines not in L1 since this iter's inv
                } else {
                    wait_agent(fL1, 8, (unsigned)(t + 1), tid, true);
                }
                ld6(Hh + l15 * H + kb0 + lk8, bh);
                ld6(Hl + l15 * H + kb0 + lk8, bl);
            }

#pragma unroll
            for (int ks = 0; ks < 6; ks++)
#pragma unroll
                for (int nt = 0; nt < 2; nt++) {
                    a2[nt] = mfma16(bh[ks], ihi[nt][ks], a2[nt]);
                    a2[nt] = mfma16(bh[ks], ilo[nt][ks], a2[nt]);
                    a2[nt] = mfma16(bl[ks], ihi[nt][ks], a2[nt]);
                }

#pragma unroll
            for (int nt = 0; nt < 2; nt++)
#pragma unroll
                for (int i = 0; i < 4; i++)
                    red[w][(lane >> 4) * 4 + i][nt * 16 + l15] = a2[nt][i];
            __syncthreads();   // full join: union => all fH2d >= t, all fL1 >= t+1

            float v0 = red[0][er][ec0] + red[1][er][ec0] + red[2][er][ec0] + red[3][er][ec0] + bsA;
            float v1 = red[0][er][ec0 + 1] + red[1][er][ec0 + 1] + red[2][er][ec0 + 1] + red[3][er][ec0 + 1] + bsB;
            v0 = tanhf(v0); v1 = tanhf(v1);
            unsigned short hb0 = f2bf(v0), hb1 = f2bf(v1);
            unsigned hp = ((unsigned)hb0) | (((unsigned)hb1) << 16);
            unsigned lp = ((unsigned)f2bf(v0 - bf2f(hb0))) | (((unsigned)f2bf(v1 - bf2f(hb1))) << 16);
            unsigned* Dh = (unsigned*)(gb + G_H2 + wb * 2 * HB_SZ) + ((long)er * H + col0 + ec0) / 2;
            unsigned* Dl = (unsigned*)(gb + G_H2 + wb * 2 * HB_SZ + HB_SZ) + ((long)er * H + col0 + ec0) / 2;
            std32<LOCAL>(Dh, hp);
            std32<LOCAL>(Dl, lp);
            red[0][er][ec0] = v0;
            red[0][er][ec0 + 1] = v1;

            DRAIN();   // h2 stores committed + red[] visible
            if (tid == 0) {
                if constexpr (LOCAL) stflag_l2(fH2d + q * 16, (unsigned)(t + 1));
                else st_ag(fH2d + q * 16, (unsigned)(t + 1));
            }

            // off the h2 critical chain: out partial
            if (tid < 32) {
                float s = 0.f;
#pragma unroll
                for (int cc = 0; cc < 32; cc++) s += red[0][ro][cc] * wl[cc];
                std32<LOCAL>((unsigned*)&Pb[(((t & 7) * 16 + ro) * 2 + oo) * 24 + q],
                             __float_as_uint(s));
            }

            DRAIN();
            if (tid == 0) {
                if constexpr (LOCAL) stflag_l2(fP + q * 16, (unsigned)(t + 1));
                else st_ag(fP + q * 16, (unsigned)(t + 1));
            }
        }
    }
}

// ---------------------------------------------------------------------------
__global__ __launch_bounds__(256, 1) void rnn_persist(
    const float* __restrict__ x,
    const float* __restrict__ Wih1, const float* __restrict__ Whh1,
    const float* __restrict__ bih1, const float* __restrict__ bhh1,
    const float* __restrict__ Wih2, const float* __restrict__ Whh2,
    const float* __restrict__ bih2, const float* __restrict__ bhh2,
    const float* __restrict__ Wlin, const float* __restrict__ blin,
    float* __restrict__ out, unsigned char* __restrict__ ws)
{
    const int wg = blockIdx.x;
    const int tid = threadIdx.x;
    const int lane = tid & 63;
    const int w = tid >> 6;
    const int l15 = lane & 15;
    const int lk8 = (lane >> 4) * 8;

    __shared__ float red[4][16][97];
    __shared__ int iscr[256];
    __shared__ unsigned shm[4];

    // ---- runtime XCD discovery (agent scope, r5/r6/r12-proven) -------------
    unsigned* map = (unsigned*)(ws + MAP_OFF);
    unsigned* kbr = (unsigned*)(ws + KBR_OFF);

    int key;
    asm volatile("s_getreg_b32 %0, hwreg(HW_REG_XCC_ID, 0, 4)" : "=s"(key));
    key &= 0xF;

    if (tid == 0) st_ag(map + wg, (unsigned)(key + 1));
    unsigned kj;
    {
        long spin = 0;
        for (;;) {
            kj = ld_ag(map + tid);
            if (kj) break;
            __builtin_amdgcn_s_sleep(2);
            if (++spin > (1L << 20)) break;
        }
    }
    int contrib = (((int)kj - 1) < key || (((int)kj - 1) == key && tid < wg)) ? 1 : 0;
    iscr[tid] = contrib;
    __syncthreads();
#pragma unroll
    for (int s = 128; s; s >>= 1) {
        if (tid < s) iscr[tid] += iscr[tid + s];
        __syncthreads();
    }
    const int rank = iscr[0];
    __syncthreads();
    const int group = rank >> 5, lrank = rank & 31;

    if (tid == 0) st_ag(kbr + rank, (unsigned)(key + 1));
    unsigned kv;
    {
        long spin = 0;
        for (;;) {
            kv = ld_ag(kbr + tid);
            if (kv) break;
            __builtin_amdgcn_s_sleep(2);
            if (++spin > (1L << 20)) break;
        }
    }
    int eq = ((int)kv - 1 == key) ? 1 : 0;
    int bad = ((tid >> 5) == group && !eq) ? 1 : 0;
    iscr[tid] = eq | (bad << 16);
    __syncthreads();
#pragma unroll
    for (int s = 128; s; s >>= 1) {
        if (tid < s) iscr[tid] += iscr[tid + s];
        __syncthreads();
    }
    const int r0 = iscr[0];
    __syncthreads();
    const bool local = ((r0 & 0xFFFF) == 32) && ((r0 >> 16) == 0);

    unsigned char* gb = ws + GRP_BASE + (size_t)group * GRP_STRIDE;

    if (local)
        run_group<true>(group, lrank, tid, lane, w, l15, lk8,
                        x, Wih1, Whh1, bih1, bhh1, Wih2, Whh2, bih2, bhh2,
                        Wlin, blin, out, gb, red, shm);
    else
        run_group<false>(group, lrank, tid, lane, w, l15, lk8,
                         x, Wih1, Whh1, bih1, bhh1, Wih2, Whh2, bih2, bhh2,
                         Wlin, blin, out, gb, red, shm);
}

extern "C" void kernel_launch(void* const* d_in, const int* in_sizes, int n_in,
                              void* d_out, int out_size, void* d_ws, size_t ws_size,
                              hipStream_t stream) {
    const float* x    = (const float*)d_in[0];
    const float* Wih1 = (const float*)d_in[1];
    const float* Whh1 = (const float*)d_in[2];
    const float* bih1 = (const float*)d_in[3];
    const float* bhh1 = (const float*)d_in[4];
    const float* Wih2 = (const float*)d_in[5];
    const float* Whh2 = (const float*)d_in[6];
    const float* bih2 = (const float*)d_in[7];
    const float* bhh2 = (const float*)d_in[8];
    const float* Wlin = (const float*)d_in[9];
    const float* blin = (const float*)d_in[10];

    // Zero discovery tables, flags, h-state (initial h = 0).
    hipMemsetAsync(d_ws, 0, WS_TOTAL, stream);

    rnn_persist<<<NWG, 256, 0, stream>>>(x, Wih1, Whh1, bih1, bhh1,
                                         Wih2, Whh2, bih2, bhh2,
                                         Wlin, blin, (float*)d_out,
                                         (unsigned char*)d_ws);
}